// Round 1
// baseline (6828.361 us; speedup 1.0000x reference)
//
#include <hip/hip_runtime.h>

#define HH 64
#define WW 64
#define HW 4096
#define CC 256
#define BB 4
#define GG 4
#define NPAIR 3

// ---------------- weight transposes ----------------
// w_def [o][c][kh][kw] -> wdefT[k][c][o]
__global__ void transpose_wdef(const float* __restrict__ wd, float* __restrict__ wdefT) {
    int idx = blockIdx.x * 256 + threadIdx.x;  // 256*256*9
    if (idx >= 256 * 256 * 9) return;
    int o = idx / (256 * 9);
    int rem = idx % (256 * 9);
    int c = rem / 9;
    int k = rem % 9;
    wdefT[(k * 256 + c) * 256 + o] = wd[idx];
}

// w_fusion [o][ci][kh][kw] -> wfusT[(ci*9+k)*256+o]
__global__ void transpose_wfus(const float* __restrict__ wf, float* __restrict__ wfusT) {
    int idx = blockIdx.x * 256 + threadIdx.x;  // 256*1024*9
    if (idx >= 256 * 1024 * 9) return;
    int o = idx / (1024 * 9);
    int rem = idx % (1024 * 9);
    int ci = rem / 9;
    int k = rem % 9;
    wfusT[(ci * 9 + k) * 256 + o] = wf[idx];
}

// ---------------- correlation ----------------
// corr[z][d][hw], z = pair*4+b, d = (di+3)*7+(dj+3), mean over 256 channels
// grid (16, 12), block 256; thread holds all 49 accumulators (static indices).
__global__ void __launch_bounds__(256) corr_kernel(const float* __restrict__ in,
                                                   float* __restrict__ corr) {
    int hw = blockIdx.x * 256 + threadIdx.x;
    int h = hw >> 6, w = hw & 63;
    int z = blockIdx.y;
    int pair = z >> 2, b = z & 3;
    const float* x1 = in + (size_t)(b * GG + pair) * CC * HW;
    const float* x2 = in + (size_t)(b * GG + 3) * CC * HW;
    float acc[49];
#pragma unroll
    for (int d = 0; d < 49; ++d) acc[d] = 0.f;
    for (int c = 0; c < CC; ++c) {
        float v1 = x1[(size_t)c * HW + hw];
        const float* p2 = x2 + (size_t)c * HW;
#pragma unroll
        for (int di = -3; di <= 3; ++di) {
            int h2 = h + 2 * di;
            if (h2 < 0 || h2 >= HH) continue;
#pragma unroll
            for (int dj = -3; dj <= 3; ++dj) {
                int w2 = w + 2 * dj;
                if (w2 < 0 || w2 >= WW) continue;
                acc[(di + 3) * 7 + (dj + 3)] += v1 * p2[h2 * WW + w2];
            }
        }
    }
    float* cp = corr + (size_t)z * 49 * HW + hw;
#pragma unroll
    for (int d = 0; d < 49; ++d) cp[(size_t)d * HW] = acc[d] * (1.f / 256.f);
}

// ---------------- offset conv (305 -> 72, 3x3, pad 1) ----------------
// grid (16, 72, 12), block 256
__global__ void __launch_bounds__(256) offconv_kernel(const float* __restrict__ in,
                                                      const float* __restrict__ corr,
                                                      const float* __restrict__ wOff,
                                                      float* __restrict__ off) {
    int hw = blockIdx.x * 256 + threadIdx.x;
    int h = hw >> 6, w = hw & 63;
    int o = blockIdx.y;
    int z = blockIdx.z;
    int pair = z >> 2, b = z & 3;
    const float* xim = in + (size_t)(b * GG + pair) * CC * HW;
    const float* cim = corr + (size_t)z * 49 * HW;
    const float* wp = wOff + (size_t)o * 305 * 9;
    float acc = 0.f;
    for (int ci = 0; ci < 305; ++ci) {
        const float* src = (ci < 256) ? (xim + (size_t)ci * HW) : (cim + (size_t)(ci - 256) * HW);
        const float* wr = wp + ci * 9;
#pragma unroll
        for (int kh = 0; kh < 3; ++kh) {
            int hh = h + kh - 1;
            if (hh < 0 || hh >= HH) continue;
            const float* srow = src + hh * WW;
#pragma unroll
            for (int kw = 0; kw < 3; ++kw) {
                int ww2 = w + kw - 1;
                if (ww2 < 0 || ww2 >= WW) continue;
                acc += srow[ww2] * wr[kh * 3 + kw];
            }
        }
    }
    off[((size_t)z * 72 + o) * HW + hw] = acc;
}

// ---------------- deformable conv ----------------
// block = 256 threads handles (pair, b, h): all 256 out channels x 64 w.
// Phase A (per k): wave g samples 64 channels of its group bilinearly -> LDS v[256][64]
// Phase B: register-blocked accumulate, thread = 8 o x 8 w tile.
// grid (64, 4, 3)
__global__ void __launch_bounds__(256, 2) deform_kernel(const float* __restrict__ in,
                                                        const float* __restrict__ off,
                                                        const float* __restrict__ wdefT,
                                                        float* __restrict__ feats) {
    __shared__ float v[256][64];
    int h = blockIdx.x, b = blockIdx.y, pair = blockIdx.z;
    int z = pair * 4 + b;
    const float* xim = in + (size_t)(b * GG + pair) * CC * HW;
    const float* offp = off + (size_t)z * 72 * HW;
    int tid = threadIdx.x;
    int lane = tid & 63;   // sampling: w
    int g = tid >> 6;      // sampling: deform group (= wave id)
    int wg = tid & 7;      // accumulate: w-group (w = wg*8+j)
    int og = tid >> 3;     // accumulate: o-group (o = og*8+i)

    float acc[8][8];
#pragma unroll
    for (int i = 0; i < 8; ++i)
#pragma unroll
        for (int j = 0; j < 8; ++j) acc[i][j] = 0.f;

    for (int k = 0; k < 9; ++k) {
        // ---- sampling phase ----
        {
            float oy = offp[(size_t)(g * 18 + k * 2 + 0) * HW + h * WW + lane];
            float ox = offp[(size_t)(g * 18 + k * 2 + 1) * HW + h * WW + lane];
            float py = (float)h + (float)(k / 3 - 1) + oy;
            float px = (float)lane + (float)(k % 3 - 1) + ox;
            float y0f = floorf(py), x0f = floorf(px);
            float fy = py - y0f, fx = px - x0f;
            int y0 = (int)y0f, x0 = (int)x0f;
            int y1 = y0 + 1, x1 = x0 + 1;
            bool vy0 = (y0 >= 0) && (y0 < HH);
            bool vy1 = (y1 >= 0) && (y1 < HH);
            bool vx0 = (x0 >= 0) && (x0 < WW);
            bool vx1 = (x1 >= 0) && (x1 < WW);
            float w00 = (1.f - fy) * (1.f - fx) * ((vy0 && vx0) ? 1.f : 0.f);
            float w01 = (1.f - fy) * fx * ((vy0 && vx1) ? 1.f : 0.f);
            float w10 = fy * (1.f - fx) * ((vy1 && vx0) ? 1.f : 0.f);
            float w11 = fy * fx * ((vy1 && vx1) ? 1.f : 0.f);
            int cy0 = min(max(y0, 0), HH - 1), cy1 = min(max(y1, 0), HH - 1);
            int cx0 = min(max(x0, 0), WW - 1), cx1 = min(max(x1, 0), WW - 1);
            int r0 = cy0 * WW, r1 = cy1 * WW;
            const float* xc = xim + (size_t)(g * 64) * HW;
#pragma unroll 4
            for (int cg = 0; cg < 64; ++cg) {
                const float* p = xc + (size_t)cg * HW;
                float s = w00 * p[r0 + cx0] + w01 * p[r0 + cx1] +
                          w10 * p[r1 + cx0] + w11 * p[r1 + cx1];
                v[g * 64 + cg][lane] = s;
            }
        }
        __syncthreads();
        // ---- accumulate phase ----
        const float* wk = wdefT + (size_t)k * 256 * 256;
        for (int c = 0; c < 256; ++c) {
            float4 v0 = *reinterpret_cast<const float4*>(&v[c][wg * 8]);
            float4 v1 = *reinterpret_cast<const float4*>(&v[c][wg * 8 + 4]);
            float vv[8] = {v0.x, v0.y, v0.z, v0.w, v1.x, v1.y, v1.z, v1.w};
            const float* wrow = wk + c * 256 + og * 8;
            float4 w0 = *reinterpret_cast<const float4*>(wrow);
            float4 w1 = *reinterpret_cast<const float4*>(wrow + 4);
            float wv[8] = {w0.x, w0.y, w0.z, w0.w, w1.x, w1.y, w1.z, w1.w};
#pragma unroll
            for (int i = 0; i < 8; ++i)
#pragma unroll
                for (int j = 0; j < 8; ++j) acc[i][j] += wv[i] * vv[j];
        }
        __syncthreads();
    }
    // write feats[z][o][h][w]
    float* fout = feats + (size_t)z * 256 * HW + h * WW;
#pragma unroll
    for (int i = 0; i < 8; ++i) {
        int o = og * 8 + i;
#pragma unroll
        for (int j = 0; j < 8; ++j) fout[(size_t)o * HW + wg * 8 + j] = acc[i][j];
    }
}

// ---------------- fusion conv (1024 -> 256, 3x3, pad 1) ----------------
// block = 256 threads handles (ot, h, b): 128 out channels x 64 w.
// thread = 8 o x 4 w register tile; input rows staged in LDS in 16-channel chunks.
// grid (2, 64, 4)
__global__ void __launch_bounds__(256, 2) fusion_kernel(const float* __restrict__ in,
                                                        const float* __restrict__ feats,
                                                        const float* __restrict__ wfusT,
                                                        float* __restrict__ out) {
    __shared__ float rows[16][3][72];
    int ot = blockIdx.x, h = blockIdx.y, b = blockIdx.z;
    int tid = threadIdx.x;
    int wg = tid & 15;   // w = wg*4 + j
    int og = tid >> 4;   // o = ot*128 + og*8 + i
    float acc[8][4];
#pragma unroll
    for (int i = 0; i < 8; ++i)
#pragma unroll
        for (int j = 0; j < 4; ++j) acc[i][j] = 0.f;

    const float* ybase = in + (size_t)(b * 4 + 3) * CC * HW;

    for (int ci0 = 0; ci0 < 1024; ci0 += 16) {
        __syncthreads();
        // stage 16 channels x 3 rows x 66 cols (col-1 = w)
        for (int idx = tid; idx < 16 * 3 * 66; idx += 256) {
            int cc = idx / (3 * 66);
            int rem = idx % (3 * 66);
            int r = rem / 66;
            int col = rem % 66;
            int cig = ci0 + cc;
            const float* src = (cig < 768)
                ? feats + ((size_t)((cig >> 8) * 4 + b) * 256 + (cig & 255)) * HW
                : ybase + (size_t)(cig - 768) * HW;
            int hh = h + r - 1;
            int wcol = col - 1;
            float val = (hh >= 0 && hh < HH && wcol >= 0 && wcol < WW) ? src[hh * WW + wcol] : 0.f;
            rows[cc][r][col] = val;
        }
        __syncthreads();
        for (int cc = 0; cc < 16; ++cc) {
            const float* wbase = wfusT + (size_t)(ci0 + cc) * 9 * 256 + ot * 128 + og * 8;
#pragma unroll
            for (int kh = 0; kh < 3; ++kh) {
                const float* rp = &rows[cc][kh][wg * 4];
                float4 i0 = *reinterpret_cast<const float4*>(rp);
                float4 i1 = *reinterpret_cast<const float4*>(rp + 4);
                float ivals[8] = {i0.x, i0.y, i0.z, i0.w, i1.x, i1.y, i1.z, i1.w};
#pragma unroll
                for (int kw = 0; kw < 3; ++kw) {
                    const float* wrow = wbase + (kh * 3 + kw) * 256;
                    float4 w0 = *reinterpret_cast<const float4*>(wrow);
                    float4 w1 = *reinterpret_cast<const float4*>(wrow + 4);
                    float wv[8] = {w0.x, w0.y, w0.z, w0.w, w1.x, w1.y, w1.z, w1.w};
#pragma unroll
                    for (int i = 0; i < 8; ++i)
#pragma unroll
                        for (int j = 0; j < 4; ++j) acc[i][j] += wv[i] * ivals[j + kw];
                }
            }
        }
    }
    float* op = out + (size_t)b * 256 * HW + h * WW;
#pragma unroll
    for (int i = 0; i < 8; ++i) {
        int o = ot * 128 + og * 8 + i;
#pragma unroll
        for (int j = 0; j < 4; ++j) op[(size_t)o * HW + wg * 4 + j] = acc[i][j];
    }
}

extern "C" void kernel_launch(void* const* d_in, const int* in_sizes, int n_in,
                              void* d_out, int out_size, void* d_ws, size_t ws_size,
                              hipStream_t stream) {
    const float* in   = (const float*)d_in[0];   // [16,256,64,64]
    const float* wOff = (const float*)d_in[1];   // [72,305,3,3]
    const float* wDef = (const float*)d_in[2];   // [256,256,3,3]
    const float* wFus = (const float*)d_in[3];   // [256,1024,3,3]
    float* out = (float*)d_out;                  // [4,256,64,64]
    float* ws = (float*)d_ws;

    float* corrB = ws;                                   // 12*49*4096
    float* offB  = corrB + (size_t)12 * 49 * HW;         // 12*72*4096
    float* feats = offB + (size_t)12 * 72 * HW;          // 12*256*4096
    float* wdefT = feats + (size_t)12 * 256 * HW;        // 9*256*256
    float* wfusT = wdefT + (size_t)9 * 256 * 256;        // 1024*9*256

    hipLaunchKernelGGL(transpose_wdef, dim3((256 * 256 * 9 + 255) / 256), dim3(256), 0, stream,
                       wDef, wdefT);
    hipLaunchKernelGGL(transpose_wfus, dim3((256 * 1024 * 9 + 255) / 256), dim3(256), 0, stream,
                       wFus, wfusT);
    hipLaunchKernelGGL(corr_kernel, dim3(16, 12), dim3(256), 0, stream, in, corrB);
    hipLaunchKernelGGL(offconv_kernel, dim3(16, 72, 12), dim3(256), 0, stream,
                       in, corrB, wOff, offB);
    hipLaunchKernelGGL(deform_kernel, dim3(64, 4, 3), dim3(256), 0, stream,
                       in, offB, wdefT, feats);
    hipLaunchKernelGGL(fusion_kernel, dim3(2, 64, 4), dim3(256), 0, stream,
                       in, feats, wfusT, out);
}

// Round 2
// 4752.334 us; speedup vs baseline: 1.4368x; 1.4368x over previous
//
#include <hip/hip_runtime.h>

#define HH 64
#define WW 64
#define HW 4096
#define CC 256
#define BB 4
#define GG 4
#define NPAIR 3

// ---------------- weight transposes ----------------
// w_def [o][c][kh][kw] -> wdefT[k][c][o]
__global__ void transpose_wdef(const float* __restrict__ wd, float* __restrict__ wdefT) {
    int idx = blockIdx.x * 256 + threadIdx.x;  // 256*256*9
    if (idx >= 256 * 256 * 9) return;
    int o = idx / (256 * 9);
    int rem = idx % (256 * 9);
    int c = rem / 9;
    int k = rem % 9;
    wdefT[(k * 256 + c) * 256 + o] = wd[idx];
}

// w_fusion [o][ci][kh][kw] -> wfusT[(ci*9+k)*256+o]
__global__ void transpose_wfus(const float* __restrict__ wf, float* __restrict__ wfusT) {
    int idx = blockIdx.x * 256 + threadIdx.x;  // 256*1024*9
    if (idx >= 256 * 1024 * 9) return;
    int o = idx / (1024 * 9);
    int rem = idx % (1024 * 9);
    int ci = rem / 9;
    int k = rem % 9;
    wfusT[(ci * 9 + k) * 256 + o] = wf[idx];
}

// w_offset [72][305][9] -> wOffT[(ci*9+k)*72 + o]
__global__ void transpose_woff(const float* __restrict__ wo, float* __restrict__ woT) {
    int idx = blockIdx.x * 256 + threadIdx.x;  // 72*305*9 = 197640
    if (idx >= 72 * 305 * 9) return;
    int o = idx / (305 * 9);
    int rem = idx % (305 * 9);
    woT[rem * 72 + o] = wo[idx];
}

// ---------------- correlation ----------------
// corr[z][d][hw], z = pair*4+b, d = (di+3)*7+(dj+3), mean over 256 channels
__global__ void __launch_bounds__(256) corr_kernel(const float* __restrict__ in,
                                                   float* __restrict__ corr) {
    int hw = blockIdx.x * 256 + threadIdx.x;
    int h = hw >> 6, w = hw & 63;
    int z = blockIdx.y;
    int pair = z >> 2, b = z & 3;
    const float* x1 = in + (size_t)(b * GG + pair) * CC * HW;
    const float* x2 = in + (size_t)(b * GG + 3) * CC * HW;
    float acc[49];
#pragma unroll
    for (int d = 0; d < 49; ++d) acc[d] = 0.f;
    for (int c = 0; c < CC; ++c) {
        float v1 = x1[(size_t)c * HW + hw];
        const float* p2 = x2 + (size_t)c * HW;
#pragma unroll
        for (int di = -3; di <= 3; ++di) {
            int h2 = h + 2 * di;
            if (h2 < 0 || h2 >= HH) continue;
#pragma unroll
            for (int dj = -3; dj <= 3; ++dj) {
                int w2 = w + 2 * dj;
                if (w2 < 0 || w2 >= WW) continue;
                acc[(di + 3) * 7 + (dj + 3)] += v1 * p2[h2 * WW + w2];
            }
        }
    }
    float* cp = corr + (size_t)z * 49 * HW + hw;
#pragma unroll
    for (int d = 0; d < 49; ++d) cp[(size_t)d * HW] = acc[d] * (1.f / 256.f);
}

// ---------------- offset conv (305 -> 72, 3x3, pad 1) ----------------
// block = 192 threads handles (h, z): all 72 out channels x 64 w.
// thread = 6 o x 4 w register tile; inputs LDS-staged in 16-ch chunks;
// weights from wOffT[(ci*9+k)*72+o] as float2 (L2-resident, in-wave broadcast).
// grid (64, 12)
__global__ void __launch_bounds__(192, 2) offconv_kernel(const float* __restrict__ in,
                                                         const float* __restrict__ corr,
                                                         const float* __restrict__ woT,
                                                         float* __restrict__ off) {
    __shared__ float rows[16][3][68];
    int h = blockIdx.x, z = blockIdx.y;
    int pair = z >> 2, b = z & 3;
    const float* xim = in + (size_t)(b * GG + pair) * CC * HW;
    const float* cim = corr + (size_t)z * 49 * HW;
    int tid = threadIdx.x;
    int wg = tid & 15;   // w = wg*4 + j
    int og = tid >> 4;   // o = og*6 + i
    float acc[6][4];
#pragma unroll
    for (int i = 0; i < 6; ++i)
#pragma unroll
        for (int j = 0; j < 4; ++j) acc[i][j] = 0.f;

    for (int ci0 = 0; ci0 < 305; ci0 += 16) {
        int ccn = min(16, 305 - ci0);
        __syncthreads();
        for (int idx = tid; idx < ccn * 3 * 66; idx += 192) {
            int cc = idx / 198;
            int rem = idx % 198;
            int r = rem / 66;
            int col = rem % 66;
            int cig = ci0 + cc;
            const float* src = (cig < 256) ? (xim + (size_t)cig * HW)
                                           : (cim + (size_t)(cig - 256) * HW);
            int hh = h + r - 1;
            int wcol = col - 1;
            rows[cc][r][col] =
                (hh >= 0 && hh < HH && wcol >= 0 && wcol < WW) ? src[hh * WW + wcol] : 0.f;
        }
        __syncthreads();
        for (int cc = 0; cc < ccn; ++cc) {
            const float* wbase = woT + (size_t)(ci0 + cc) * 9 * 72 + og * 6;
#pragma unroll
            for (int kh = 0; kh < 3; ++kh) {
                const float* rp = &rows[cc][kh][wg * 4];
                float4 i0 = *reinterpret_cast<const float4*>(rp);
                float iv[6] = {i0.x, i0.y, i0.z, i0.w, rp[4], rp[5]};
#pragma unroll
                for (int kw = 0; kw < 3; ++kw) {
                    const float* wr = wbase + (kh * 3 + kw) * 72;
                    float2 w0 = *reinterpret_cast<const float2*>(wr);
                    float2 w1 = *reinterpret_cast<const float2*>(wr + 2);
                    float2 w2 = *reinterpret_cast<const float2*>(wr + 4);
                    float wv[6] = {w0.x, w0.y, w1.x, w1.y, w2.x, w2.y};
#pragma unroll
                    for (int i = 0; i < 6; ++i)
#pragma unroll
                        for (int j = 0; j < 4; ++j) acc[i][j] += wv[i] * iv[j + kw];
                }
            }
        }
    }
    float* op = off + (size_t)z * 72 * HW + h * WW;
#pragma unroll
    for (int i = 0; i < 6; ++i) {
        int o = og * 6 + i;
#pragma unroll
        for (int j = 0; j < 4; ++j) op[(size_t)o * HW + wg * 4 + j] = acc[i][j];
    }
}

// ---------------- deformable conv ----------------
// grid (64, 4, 3), block 256
__global__ void __launch_bounds__(256, 2) deform_kernel(const float* __restrict__ in,
                                                        const float* __restrict__ off,
                                                        const float* __restrict__ wdefT,
                                                        float* __restrict__ feats) {
    __shared__ float v[256][64];
    int h = blockIdx.x, b = blockIdx.y, pair = blockIdx.z;
    int z = pair * 4 + b;
    const float* xim = in + (size_t)(b * GG + pair) * CC * HW;
    const float* offp = off + (size_t)z * 72 * HW;
    int tid = threadIdx.x;
    int lane = tid & 63;   // sampling: w
    int g = tid >> 6;      // sampling: deform group (= wave id)
    int wg = tid & 7;      // accumulate: w-group (w = wg*8+j)
    int og = tid >> 3;     // accumulate: o-group (o = og*8+i)

    float acc[8][8];
#pragma unroll
    for (int i = 0; i < 8; ++i)
#pragma unroll
        for (int j = 0; j < 8; ++j) acc[i][j] = 0.f;

    for (int k = 0; k < 9; ++k) {
        {
            float oy = offp[(size_t)(g * 18 + k * 2 + 0) * HW + h * WW + lane];
            float ox = offp[(size_t)(g * 18 + k * 2 + 1) * HW + h * WW + lane];
            float py = (float)h + (float)(k / 3 - 1) + oy;
            float px = (float)lane + (float)(k % 3 - 1) + ox;
            float y0f = floorf(py), x0f = floorf(px);
            float fy = py - y0f, fx = px - x0f;
            int y0 = (int)y0f, x0 = (int)x0f;
            int y1 = y0 + 1, x1 = x0 + 1;
            bool vy0 = (y0 >= 0) && (y0 < HH);
            bool vy1 = (y1 >= 0) && (y1 < HH);
            bool vx0 = (x0 >= 0) && (x0 < WW);
            bool vx1 = (x1 >= 0) && (x1 < WW);
            float w00 = (1.f - fy) * (1.f - fx) * ((vy0 && vx0) ? 1.f : 0.f);
            float w01 = (1.f - fy) * fx * ((vy0 && vx1) ? 1.f : 0.f);
            float w10 = fy * (1.f - fx) * ((vy1 && vx0) ? 1.f : 0.f);
            float w11 = fy * fx * ((vy1 && vx1) ? 1.f : 0.f);
            int cy0 = min(max(y0, 0), HH - 1), cy1 = min(max(y1, 0), HH - 1);
            int cx0 = min(max(x0, 0), WW - 1), cx1 = min(max(x1, 0), WW - 1);
            int r0 = cy0 * WW, r1 = cy1 * WW;
            const float* xc = xim + (size_t)(g * 64) * HW;
#pragma unroll 4
            for (int cg = 0; cg < 64; ++cg) {
                const float* p = xc + (size_t)cg * HW;
                float s = w00 * p[r0 + cx0] + w01 * p[r0 + cx1] +
                          w10 * p[r1 + cx0] + w11 * p[r1 + cx1];
                v[g * 64 + cg][lane] = s;
            }
        }
        __syncthreads();
        const float* wk = wdefT + (size_t)k * 256 * 256;
        for (int c = 0; c < 256; ++c) {
            float4 v0 = *reinterpret_cast<const float4*>(&v[c][wg * 8]);
            float4 v1 = *reinterpret_cast<const float4*>(&v[c][wg * 8 + 4]);
            float vv[8] = {v0.x, v0.y, v0.z, v0.w, v1.x, v1.y, v1.z, v1.w};
            const float* wrow = wk + c * 256 + og * 8;
            float4 w0 = *reinterpret_cast<const float4*>(wrow);
            float4 w1 = *reinterpret_cast<const float4*>(wrow + 4);
            float wv[8] = {w0.x, w0.y, w0.z, w0.w, w1.x, w1.y, w1.z, w1.w};
#pragma unroll
            for (int i = 0; i < 8; ++i)
#pragma unroll
                for (int j = 0; j < 8; ++j) acc[i][j] += wv[i] * vv[j];
        }
        __syncthreads();
    }
    float* fout = feats + (size_t)z * 256 * HW + h * WW;
#pragma unroll
    for (int i = 0; i < 8; ++i) {
        int o = og * 8 + i;
#pragma unroll
        for (int j = 0; j < 8; ++j) fout[(size_t)o * HW + wg * 8 + j] = acc[i][j];
    }
}

// ---------------- fusion conv (1024 -> 256, 3x3, pad 1) ----------------
// grid (2, 64, 4), block 256
__global__ void __launch_bounds__(256, 2) fusion_kernel(const float* __restrict__ in,
                                                        const float* __restrict__ feats,
                                                        const float* __restrict__ wfusT,
                                                        float* __restrict__ out) {
    __shared__ float rows[16][3][72];
    int ot = blockIdx.x, h = blockIdx.y, b = blockIdx.z;
    int tid = threadIdx.x;
    int wg = tid & 15;   // w = wg*4 + j
    int og = tid >> 4;   // o = ot*128 + og*8 + i
    float acc[8][4];
#pragma unroll
    for (int i = 0; i < 8; ++i)
#pragma unroll
        for (int j = 0; j < 4; ++j) acc[i][j] = 0.f;

    const float* ybase = in + (size_t)(b * 4 + 3) * CC * HW;

    for (int ci0 = 0; ci0 < 1024; ci0 += 16) {
        __syncthreads();
        for (int idx = tid; idx < 16 * 3 * 66; idx += 256) {
            int cc = idx / (3 * 66);
            int rem = idx % (3 * 66);
            int r = rem / 66;
            int col = rem % 66;
            int cig = ci0 + cc;
            const float* src = (cig < 768)
                ? feats + ((size_t)((cig >> 8) * 4 + b) * 256 + (cig & 255)) * HW
                : ybase + (size_t)(cig - 768) * HW;
            int hh = h + r - 1;
            int wcol = col - 1;
            float val = (hh >= 0 && hh < HH && wcol >= 0 && wcol < WW) ? src[hh * WW + wcol] : 0.f;
            rows[cc][r][col] = val;
        }
        __syncthreads();
        for (int cc = 0; cc < 16; ++cc) {
            const float* wbase = wfusT + (size_t)(ci0 + cc) * 9 * 256 + ot * 128 + og * 8;
#pragma unroll
            for (int kh = 0; kh < 3; ++kh) {
                const float* rp = &rows[cc][kh][wg * 4];
                float4 i0 = *reinterpret_cast<const float4*>(rp);
                float4 i1 = *reinterpret_cast<const float4*>(rp + 4);
                float ivals[8] = {i0.x, i0.y, i0.z, i0.w, i1.x, i1.y, i1.z, i1.w};
#pragma unroll
                for (int kw = 0; kw < 3; ++kw) {
                    const float* wrow = wbase + (kh * 3 + kw) * 256;
                    float4 w0 = *reinterpret_cast<const float4*>(wrow);
                    float4 w1 = *reinterpret_cast<const float4*>(wrow + 4);
                    float wv[8] = {w0.x, w0.y, w0.z, w0.w, w1.x, w1.y, w1.z, w1.w};
#pragma unroll
                    for (int i = 0; i < 8; ++i)
#pragma unroll
                        for (int j = 0; j < 4; ++j) acc[i][j] += wv[i] * ivals[j + kw];
                }
            }
        }
    }
    float* op = out + (size_t)b * 256 * HW + h * WW;
#pragma unroll
    for (int i = 0; i < 8; ++i) {
        int o = ot * 128 + og * 8 + i;
#pragma unroll
        for (int j = 0; j < 4; ++j) op[(size_t)o * HW + wg * 4 + j] = acc[i][j];
    }
}

extern "C" void kernel_launch(void* const* d_in, const int* in_sizes, int n_in,
                              void* d_out, int out_size, void* d_ws, size_t ws_size,
                              hipStream_t stream) {
    const float* in   = (const float*)d_in[0];   // [16,256,64,64]
    const float* wOff = (const float*)d_in[1];   // [72,305,3,3]
    const float* wDef = (const float*)d_in[2];   // [256,256,3,3]
    const float* wFus = (const float*)d_in[3];   // [256,1024,3,3]
    float* out = (float*)d_out;                  // [4,256,64,64]
    float* ws = (float*)d_ws;

    float* corrB = ws;                                   // 12*49*4096
    float* offB  = corrB + (size_t)12 * 49 * HW;         // 12*72*4096
    float* feats = offB + (size_t)12 * 72 * HW;          // 12*256*4096
    float* wdefT = feats + (size_t)12 * 256 * HW;        // 9*256*256
    float* wfusT = wdefT + (size_t)9 * 256 * 256;        // 1024*9*256
    float* woT   = wfusT + (size_t)1024 * 9 * 256;       // 305*9*72

    hipLaunchKernelGGL(transpose_wdef, dim3((256 * 256 * 9 + 255) / 256), dim3(256), 0, stream,
                       wDef, wdefT);
    hipLaunchKernelGGL(transpose_wfus, dim3((256 * 1024 * 9 + 255) / 256), dim3(256), 0, stream,
                       wFus, wfusT);
    hipLaunchKernelGGL(transpose_woff, dim3((72 * 305 * 9 + 255) / 256), dim3(256), 0, stream,
                       wOff, woT);
    hipLaunchKernelGGL(corr_kernel, dim3(16, 12), dim3(256), 0, stream, in, corrB);
    hipLaunchKernelGGL(offconv_kernel, dim3(64, 12), dim3(192), 0, stream,
                       in, corrB, woT, offB);
    hipLaunchKernelGGL(deform_kernel, dim3(64, 4, 3), dim3(256), 0, stream,
                       in, offB, wdefT, feats);
    hipLaunchKernelGGL(fusion_kernel, dim3(2, 64, 4), dim3(256), 0, stream,
                       in, feats, wfusT, out);
}

// Round 3
// 3314.449 us; speedup vs baseline: 2.0602x; 1.4338x over previous
//
#include <hip/hip_runtime.h>

#define HH 64
#define WW 64
#define HW 4096
#define CC 256
#define BB 4
#define GG 4
#define NPAIR 3

typedef __attribute__((ext_vector_type(8))) short short8;
typedef __attribute__((ext_vector_type(4))) float f32x4;
typedef unsigned short ushort_t;

__device__ inline ushort_t f2bf(float x) {
    unsigned int u = __float_as_uint(x);
    unsigned int r = (u + 0x7fffu + ((u >> 16) & 1u)) >> 16;
    return (ushort_t)r;
}

// ---------------- weight transposes ----------------
// w_def [o][c][kh][kw] -> wdefT[k][c][o]  (fp32, used by deform)
__global__ void transpose_wdef(const float* __restrict__ wd, float* __restrict__ wdefT) {
    int idx = blockIdx.x * 256 + threadIdx.x;  // 256*256*9
    if (idx >= 256 * 256 * 9) return;
    int o = idx / (256 * 9);
    int rem = idx % (256 * 9);
    int c = rem / 9;
    int k = rem % 9;
    wdefT[(k * 256 + c) * 256 + o] = wd[idx];
}

// w_offset [72][305][9] -> wOffT[(ci*9+k)*72 + o]  (fp32)
__global__ void transpose_woff(const float* __restrict__ wo, float* __restrict__ woT) {
    int idx = blockIdx.x * 256 + threadIdx.x;  // 72*305*9
    if (idx >= 72 * 305 * 9) return;
    int o = idx / (305 * 9);
    int rem = idx % (305 * 9);
    woT[rem * 72 + o] = wo[idx];
}

// w_fusion [o][ci][3][3] fp32 -> wfusMF[k][o][ci] bf16
__global__ void prep_wfus(const float* __restrict__ wf, ushort_t* __restrict__ wmf) {
    int idx = blockIdx.x * 256 + threadIdx.x;  // 9*256*1024
    if (idx >= 9 * 256 * 1024) return;
    int k = idx / (256 * 1024);
    int rem = idx % (256 * 1024);
    int o = rem / 1024;
    int ci = rem % 1024;
    wmf[idx] = f2bf(wf[((size_t)o * 1024 + ci) * 9 + k]);
}

// ---------------- correlation ----------------
__global__ void __launch_bounds__(256) corr_kernel(const float* __restrict__ in,
                                                   float* __restrict__ corr) {
    int hw = blockIdx.x * 256 + threadIdx.x;
    int h = hw >> 6, w = hw & 63;
    int z = blockIdx.y;
    int pair = z >> 2, b = z & 3;
    const float* x1 = in + (size_t)(b * GG + pair) * CC * HW;
    const float* x2 = in + (size_t)(b * GG + 3) * CC * HW;
    float acc[49];
#pragma unroll
    for (int d = 0; d < 49; ++d) acc[d] = 0.f;
    for (int c = 0; c < CC; ++c) {
        float v1 = x1[(size_t)c * HW + hw];
        const float* p2 = x2 + (size_t)c * HW;
#pragma unroll
        for (int di = -3; di <= 3; ++di) {
            int h2 = h + 2 * di;
            if (h2 < 0 || h2 >= HH) continue;
#pragma unroll
            for (int dj = -3; dj <= 3; ++dj) {
                int w2 = w + 2 * dj;
                if (w2 < 0 || w2 >= WW) continue;
                acc[(di + 3) * 7 + (dj + 3)] += v1 * p2[h2 * WW + w2];
            }
        }
    }
    float* cp = corr + (size_t)z * 49 * HW + hw;
#pragma unroll
    for (int d = 0; d < 49; ++d) cp[(size_t)d * HW] = acc[d] * (1.f / 256.f);
}

// ---------------- offset conv (305 -> 72, 3x3, pad 1) ----------------
__global__ void __launch_bounds__(192, 2) offconv_kernel(const float* __restrict__ in,
                                                         const float* __restrict__ corr,
                                                         const float* __restrict__ woT,
                                                         float* __restrict__ off) {
    __shared__ float rows[16][3][68];
    int h = blockIdx.x, z = blockIdx.y;
    int pair = z >> 2, b = z & 3;
    const float* xim = in + (size_t)(b * GG + pair) * CC * HW;
    const float* cim = corr + (size_t)z * 49 * HW;
    int tid = threadIdx.x;
    int wg = tid & 15;
    int og = tid >> 4;
    float acc[6][4];
#pragma unroll
    for (int i = 0; i < 6; ++i)
#pragma unroll
        for (int j = 0; j < 4; ++j) acc[i][j] = 0.f;

    for (int ci0 = 0; ci0 < 305; ci0 += 16) {
        int ccn = min(16, 305 - ci0);
        __syncthreads();
        for (int idx = tid; idx < ccn * 3 * 66; idx += 192) {
            int cc = idx / 198;
            int rem = idx % 198;
            int r = rem / 66;
            int col = rem % 66;
            int cig = ci0 + cc;
            const float* src = (cig < 256) ? (xim + (size_t)cig * HW)
                                           : (cim + (size_t)(cig - 256) * HW);
            int hh = h + r - 1;
            int wcol = col - 1;
            rows[cc][r][col] =
                (hh >= 0 && hh < HH && wcol >= 0 && wcol < WW) ? src[hh * WW + wcol] : 0.f;
        }
        __syncthreads();
        for (int cc = 0; cc < ccn; ++cc) {
            const float* wbase = woT + (size_t)(ci0 + cc) * 9 * 72 + og * 6;
#pragma unroll
            for (int kh = 0; kh < 3; ++kh) {
                const float* rp = &rows[cc][kh][wg * 4];
                float4 i0 = *reinterpret_cast<const float4*>(rp);
                float iv[6] = {i0.x, i0.y, i0.z, i0.w, rp[4], rp[5]};
#pragma unroll
                for (int kw = 0; kw < 3; ++kw) {
                    const float* wr = wbase + (kh * 3 + kw) * 72;
                    float2 w0 = *reinterpret_cast<const float2*>(wr);
                    float2 w1 = *reinterpret_cast<const float2*>(wr + 2);
                    float2 w2 = *reinterpret_cast<const float2*>(wr + 4);
                    float wv[6] = {w0.x, w0.y, w1.x, w1.y, w2.x, w2.y};
#pragma unroll
                    for (int i = 0; i < 6; ++i)
#pragma unroll
                        for (int j = 0; j < 4; ++j) acc[i][j] += wv[i] * iv[j + kw];
                }
            }
        }
    }
    float* op = off + (size_t)z * 72 * HW + h * WW;
#pragma unroll
    for (int i = 0; i < 6; ++i) {
        int o = og * 6 + i;
#pragma unroll
        for (int j = 0; j < 4; ++j) op[(size_t)o * HW + wg * 4 + j] = acc[i][j];
    }
}

// ---------------- deformable conv (fp32 VALU, unchanged) ----------------
__global__ void __launch_bounds__(256, 2) deform_kernel(const float* __restrict__ in,
                                                        const float* __restrict__ off,
                                                        const float* __restrict__ wdefT,
                                                        float* __restrict__ feats) {
    __shared__ float v[256][64];
    int h = blockIdx.x, b = blockIdx.y, pair = blockIdx.z;
    int z = pair * 4 + b;
    const float* xim = in + (size_t)(b * GG + pair) * CC * HW;
    const float* offp = off + (size_t)z * 72 * HW;
    int tid = threadIdx.x;
    int lane = tid & 63;
    int g = tid >> 6;
    int wg = tid & 7;
    int og = tid >> 3;

    float acc[8][8];
#pragma unroll
    for (int i = 0; i < 8; ++i)
#pragma unroll
        for (int j = 0; j < 8; ++j) acc[i][j] = 0.f;

    for (int k = 0; k < 9; ++k) {
        {
            float oy = offp[(size_t)(g * 18 + k * 2 + 0) * HW + h * WW + lane];
            float ox = offp[(size_t)(g * 18 + k * 2 + 1) * HW + h * WW + lane];
            float py = (float)h + (float)(k / 3 - 1) + oy;
            float px = (float)lane + (float)(k % 3 - 1) + ox;
            float y0f = floorf(py), x0f = floorf(px);
            float fy = py - y0f, fx = px - x0f;
            int y0 = (int)y0f, x0 = (int)x0f;
            int y1 = y0 + 1, x1 = x0 + 1;
            bool vy0 = (y0 >= 0) && (y0 < HH);
            bool vy1 = (y1 >= 0) && (y1 < HH);
            bool vx0 = (x0 >= 0) && (x0 < WW);
            bool vx1 = (x1 >= 0) && (x1 < WW);
            float w00 = (1.f - fy) * (1.f - fx) * ((vy0 && vx0) ? 1.f : 0.f);
            float w01 = (1.f - fy) * fx * ((vy0 && vx1) ? 1.f : 0.f);
            float w10 = fy * (1.f - fx) * ((vy1 && vx0) ? 1.f : 0.f);
            float w11 = fy * fx * ((vy1 && vx1) ? 1.f : 0.f);
            int cy0 = min(max(y0, 0), HH - 1), cy1 = min(max(y1, 0), HH - 1);
            int cx0 = min(max(x0, 0), WW - 1), cx1 = min(max(x1, 0), WW - 1);
            int r0 = cy0 * WW, r1 = cy1 * WW;
            const float* xc = xim + (size_t)(g * 64) * HW;
#pragma unroll 4
            for (int cg = 0; cg < 64; ++cg) {
                const float* p = xc + (size_t)cg * HW;
                float s = w00 * p[r0 + cx0] + w01 * p[r0 + cx1] +
                          w10 * p[r1 + cx0] + w11 * p[r1 + cx1];
                v[g * 64 + cg][lane] = s;
            }
        }
        __syncthreads();
        const float* wk = wdefT + (size_t)k * 256 * 256;
        for (int c = 0; c < 256; ++c) {
            float4 v0 = *reinterpret_cast<const float4*>(&v[c][wg * 8]);
            float4 v1 = *reinterpret_cast<const float4*>(&v[c][wg * 8 + 4]);
            float vv[8] = {v0.x, v0.y, v0.z, v0.w, v1.x, v1.y, v1.z, v1.w};
            const float* wrow = wk + c * 256 + og * 8;
            float4 w0 = *reinterpret_cast<const float4*>(wrow);
            float4 w1 = *reinterpret_cast<const float4*>(wrow + 4);
            float wv[8] = {w0.x, w0.y, w0.z, w0.w, w1.x, w1.y, w1.z, w1.w};
#pragma unroll
            for (int i = 0; i < 8; ++i)
#pragma unroll
                for (int j = 0; j < 8; ++j) acc[i][j] += wv[i] * vv[j];
        }
        __syncthreads();
    }
    float* fout = feats + (size_t)z * 256 * HW + h * WW;
#pragma unroll
    for (int i = 0; i < 8; ++i) {
        int o = og * 8 + i;
#pragma unroll
        for (int j = 0; j < 8; ++j) fout[(size_t)o * HW + wg * 8 + j] = acc[i][j];
    }
}

// ---------------- FT build: feats(+y) fp32 [c][hw] -> FT bf16 [b][hw][1024] ----------------
// grid (64, 16, 4) block 256: 64-hw x 64-ci tile via LDS transpose.
__global__ void __launch_bounds__(256) ft_build(const float* __restrict__ in,
                                                const float* __restrict__ feats,
                                                ushort_t* __restrict__ FT) {
    __shared__ ushort_t tileT[64][72];
    int hw0 = blockIdx.x * 64;
    int ci0 = blockIdx.y * 64;
    int b = blockIdx.z;
    int t = threadIdx.x;
    int cil = t >> 2, q = t & 3;
    int cig = ci0 + cil;
    const float* src = (cig < 768)
        ? feats + ((size_t)((cig >> 8) * 4 + b) * 256 + (cig & 255)) * HW
        : in + ((size_t)(b * 4 + 3) * 256 + (size_t)(cig - 768)) * HW;
    const float* sp = src + hw0 + q * 16;
#pragma unroll
    for (int i = 0; i < 16; ++i) tileT[q * 16 + i][cil] = f2bf(sp[i]);
    __syncthreads();
    int hwl = t >> 2;
    const uint4* tp = reinterpret_cast<const uint4*>(&tileT[hwl][q * 16]);
    uint4* op = reinterpret_cast<uint4*>(&FT[((size_t)b * HW + hw0 + hwl) * 1024 + ci0 + q * 16]);
    op[0] = tp[0];
    op[1] = tp[1];
}

// ---------------- fusion conv via MFMA bf16 ----------------
// O[o][hw] = sum_{tap,ci} W[o][ci,tap] * FT[hw'][ci],  hw' = hw + (kh-1)*64 + (kw-1)
// tile 64(o) x 128(hw); 4 waves, each wave: full 64 o x 32 hw slice (4x2 frags 16x16).
// grid (4, 32, 4) block 256
__global__ void __launch_bounds__(256, 2) fusion_mfma(const ushort_t* __restrict__ FT,
                                                      const ushort_t* __restrict__ wmf,
                                                      float* __restrict__ out) {
    __shared__ ushort_t a_lds[64][40];    // [o][ci] bf16
    __shared__ ushort_t b_lds[128][40];   // [hw][ci] bf16
    int o0 = blockIdx.x * 64;
    int n0 = blockIdx.y * 128;
    int b = blockIdx.z;
    int t = threadIdx.x;
    int wid = t >> 6;
    int lane = t & 63;
    int l15 = lane & 15;
    int kq = lane >> 4;
    int r2 = t >> 1, half = t & 1;
    int hwB = n0 + r2;
    int hB = hwB >> 6, wB = hwB & 63;
    const ushort_t* ftb = FT + (size_t)b * HW * 1024;

    f32x4 acc[4][2];
#pragma unroll
    for (int fm = 0; fm < 4; ++fm)
#pragma unroll
        for (int fn = 0; fn < 2; ++fn) acc[fm][fn] = (f32x4){0.f, 0.f, 0.f, 0.f};

    for (int kk = 0; kk < 288; ++kk) {
        int tap = kk >> 5;
        int ci0 = (kk & 31) << 5;
        int kh = tap / 3;
        int kw = tap - kh * 3;
        // ---- stage B: values (all 256 threads; row r2, 16-ci half) ----
        int hP = hB + kh - 1;
        int wP = wB + kw - 1;
        bool valid = (hP >= 0) && (hP < HH) && (wP >= 0) && (wP < WW);
        uint4 vb0 = make_uint4(0, 0, 0, 0), vb1 = make_uint4(0, 0, 0, 0);
        if (valid) {
            const uint4* gp = reinterpret_cast<const uint4*>(
                ftb + (size_t)(hP * WW + wP) * 1024 + ci0 + half * 16);
            vb0 = gp[0];
            vb1 = gp[1];
        }
        // ---- stage A: weights (threads 0..127; row t>>1, 16-ci half) ----
        uint4 va0, va1;
        if (t < 128) {
            const uint4* ga = reinterpret_cast<const uint4*>(
                wmf + ((size_t)(tap * 256 + o0 + r2) << 10) + ci0 + half * 16);
            va0 = ga[0];
            va1 = ga[1];
        }
        __syncthreads();
        {
            uint4* bp = reinterpret_cast<uint4*>(&b_lds[r2][half * 16]);
            bp[0] = vb0;
            bp[1] = vb1;
            if (t < 128) {
                uint4* ap = reinterpret_cast<uint4*>(&a_lds[r2][half * 16]);
                ap[0] = va0;
                ap[1] = va1;
            }
        }
        __syncthreads();
        // ---- compute ----
        short8 af[4], bf[2];
#pragma unroll
        for (int fm = 0; fm < 4; ++fm)
            af[fm] = *reinterpret_cast<const short8*>(&a_lds[fm * 16 + l15][kq * 8]);
#pragma unroll
        for (int fn = 0; fn < 2; ++fn)
            bf[fn] = *reinterpret_cast<const short8*>(&b_lds[wid * 32 + fn * 16 + l15][kq * 8]);
#pragma unroll
        for (int fm = 0; fm < 4; ++fm)
#pragma unroll
            for (int fn = 0; fn < 2; ++fn)
                acc[fm][fn] = __builtin_amdgcn_mfma_f32_16x16x32_bf16(af[fm], bf[fn],
                                                                      acc[fm][fn], 0, 0, 0);
    }
    // ---- epilogue ----
    float* ob = out + ((size_t)b * 256 + o0) * HW + n0 + wid * 32;
#pragma unroll
    for (int fm = 0; fm < 4; ++fm)
#pragma unroll
        for (int fn = 0; fn < 2; ++fn)
#pragma unroll
            for (int e = 0; e < 4; ++e) {
                int o_l = fm * 16 + 4 * kq + e;
                ob[(size_t)o_l * HW + fn * 16 + l15] = acc[fm][fn][e];
            }
}

extern "C" void kernel_launch(void* const* d_in, const int* in_sizes, int n_in,
                              void* d_out, int out_size, void* d_ws, size_t ws_size,
                              hipStream_t stream) {
    const float* in   = (const float*)d_in[0];   // [16,256,64,64]
    const float* wOff = (const float*)d_in[1];   // [72,305,3,3]
    const float* wDef = (const float*)d_in[2];   // [256,256,3,3]
    const float* wFus = (const float*)d_in[3];   // [256,1024,3,3]
    float* out = (float*)d_out;                  // [4,256,64,64]
    char* base = (char*)d_ws;

    // FT (bf16, 33.5 MB) overlays corr (9.6 MB) + off (14.2 MB): both are dead
    // before ft_build runs (corr consumed by offconv, off consumed by deform).
    ushort_t* FT    = (ushort_t*)base;                          // 4*4096*1024*2 = 33,554,432
    float* corrB    = (float*)base;                             // 12*49*4096*4 =  9,633,792
    float* offB     = (float*)(base + 9633792);                 // 12*72*4096*4 = 14,155,776
    float* feats    = (float*)(base + 33554432);                // 12*256*4096*4 = 50,331,648
    float* wdefT    = (float*)(base + 83886080);                // 9*256*256*4 = 2,359,296
    float* woT      = (float*)(base + 86245376);                // 305*9*72*4 = 790,560
    ushort_t* wfusMF = (ushort_t*)(base + 87035936);            // 9*256*1024*2 = 4,718,592

    hipLaunchKernelGGL(transpose_wdef, dim3((256 * 256 * 9 + 255) / 256), dim3(256), 0, stream,
                       wDef, wdefT);
    hipLaunchKernelGGL(transpose_woff, dim3((72 * 305 * 9 + 255) / 256), dim3(256), 0, stream,
                       wOff, woT);
    hipLaunchKernelGGL(prep_wfus, dim3((9 * 256 * 1024 + 255) / 256), dim3(256), 0, stream,
                       wFus, wfusMF);
    hipLaunchKernelGGL(corr_kernel, dim3(16, 12), dim3(256), 0, stream, in, corrB);
    hipLaunchKernelGGL(offconv_kernel, dim3(64, 12), dim3(192), 0, stream,
                       in, corrB, woT, offB);
    hipLaunchKernelGGL(deform_kernel, dim3(64, 4, 3), dim3(256), 0, stream,
                       in, offB, wdefT, feats);
    hipLaunchKernelGGL(ft_build, dim3(64, 16, 4), dim3(256), 0, stream, in, feats, FT);
    hipLaunchKernelGGL(fusion_mfma, dim3(4, 32, 4), dim3(256), 0, stream, FT, wfusMF, out);
}

// Round 4
// 2181.614 us; speedup vs baseline: 3.1300x; 1.5193x over previous
//
#include <hip/hip_runtime.h>

#define HH 64
#define WW 64
#define HW 4096
#define CC 256
#define BB 4
#define GG 4
#define NPAIR 3

typedef __attribute__((ext_vector_type(8))) short short8;
typedef __attribute__((ext_vector_type(4))) float f32x4;
typedef unsigned short ushort_t;

__device__ inline ushort_t f2bf(float x) {
    unsigned int u = __float_as_uint(x);
    unsigned int r = (u + 0x7fffu + ((u >> 16) & 1u)) >> 16;
    return (ushort_t)r;
}

// ---------------- weight transposes ----------------
// w_def [o][c][kh][kw] -> wdefT[k][c][o]  (fp32, used by deform)
__global__ void transpose_wdef(const float* __restrict__ wd, float* __restrict__ wdefT) {
    int idx = blockIdx.x * 256 + threadIdx.x;  // 256*256*9
    if (idx >= 256 * 256 * 9) return;
    int o = idx / (256 * 9);
    int rem = idx % (256 * 9);
    int c = rem / 9;
    int k = rem % 9;
    wdefT[(k * 256 + c) * 256 + o] = wd[idx];
}

// w_offset [72][305][9] -> wOffT[(ci*9+k)*72 + o]  (fp32)
__global__ void transpose_woff(const float* __restrict__ wo, float* __restrict__ woT) {
    int idx = blockIdx.x * 256 + threadIdx.x;  // 72*305*9
    if (idx >= 72 * 305 * 9) return;
    int o = idx / (305 * 9);
    int rem = idx % (305 * 9);
    woT[rem * 72 + o] = wo[idx];
}

// w_fusion [o][ci][3][3] fp32 -> wfusMF[k][o][ci] bf16
__global__ void prep_wfus(const float* __restrict__ wf, ushort_t* __restrict__ wmf) {
    int idx = blockIdx.x * 256 + threadIdx.x;  // 9*256*1024
    if (idx >= 9 * 256 * 1024) return;
    int k = idx / (256 * 1024);
    int rem = idx % (256 * 1024);
    int o = rem / 1024;
    int ci = rem % 1024;
    wmf[idx] = f2bf(wf[((size_t)o * 1024 + ci) * 9 + k]);
}

// ---------------- correlation (LDS-staged, 7-row window) ----------------
// grid (64 h, 12 z), block 256 = 64 w x 4 di-groups.
// Per 8-channel chunk: stage x1 row [8][64] + x2 7 rows padded [8][7][76];
// thread accumulates up to 2 di x 7 dj outputs (branch-free inner loop).
__global__ void __launch_bounds__(256, 2) corr_kernel(const float* __restrict__ in,
                                                      float* __restrict__ corr) {
    __shared__ float x1l[8][64];
    __shared__ float x2l[8][7][76];
    int h = blockIdx.x, z = blockIdx.y;
    int pair = z >> 2, b = z & 3;
    const float* x1 = in + (size_t)(b * GG + pair) * CC * HW + h * WW;
    const float* x2 = in + (size_t)(b * GG + 3) * CC * HW;
    int tid = threadIdx.x;
    int w = tid & 63;
    int dg = tid >> 6;  // wave id = di-group

    float acc[2][7];
#pragma unroll
    for (int i = 0; i < 2; ++i)
#pragma unroll
        for (int j = 0; j < 7; ++j) acc[i][j] = 0.f;

    for (int c0 = 0; c0 < CC; c0 += 8) {
        __syncthreads();
        // stage x1: 8 x 64
#pragma unroll
        for (int idx = tid; idx < 512; idx += 256) {
            int cc = idx >> 6, ww = idx & 63;
            x1l[cc][ww] = x1[(size_t)(c0 + cc) * HW + ww];
        }
        // stage x2: 8 x 7 x 76, zero-padded rows/cols
        for (int idx = tid; idx < 8 * 7 * 76; idx += 256) {
            int cc = idx / 532;
            int rem = idx - cc * 532;
            int r = rem / 76;
            int cl = rem - r * 76;
            int row = h + 2 * (r - 3);
            int col = cl - 6;
            float v = 0.f;
            if (row >= 0 && row < HH && col >= 0 && col < WW)
                v = x2[(size_t)(c0 + cc) * HW + row * WW + col];
            x2l[cc][r][cl] = v;
        }
        __syncthreads();
#pragma unroll
        for (int cc = 0; cc < 8; ++cc) {
            float x1v = x1l[cc][w];
#pragma unroll
            for (int i = 0; i < 2; ++i) {
                int di = dg * 2 + i;
                if (di < 7) {  // wave-uniform
#pragma unroll
                    for (int dj = 0; dj < 7; ++dj)
                        acc[i][dj] += x1v * x2l[cc][di][w + 2 * dj];
                }
            }
        }
    }
    float* cp = corr + (size_t)z * 49 * HW + h * WW + w;
#pragma unroll
    for (int i = 0; i < 2; ++i) {
        int di = dg * 2 + i;
        if (di < 7) {
#pragma unroll
            for (int dj = 0; dj < 7; ++dj)
                cp[(size_t)(di * 7 + dj) * HW] = acc[i][dj] * (1.f / 256.f);
        }
    }
}

// ---------------- offset conv (305 -> 72, 3x3, pad 1) ----------------
__global__ void __launch_bounds__(192, 2) offconv_kernel(const float* __restrict__ in,
                                                         const float* __restrict__ corr,
                                                         const float* __restrict__ woT,
                                                         float* __restrict__ off) {
    __shared__ float rows[16][3][68];
    int h = blockIdx.x, z = blockIdx.y;
    int pair = z >> 2, b = z & 3;
    const float* xim = in + (size_t)(b * GG + pair) * CC * HW;
    const float* cim = corr + (size_t)z * 49 * HW;
    int tid = threadIdx.x;
    int wg = tid & 15;
    int og = tid >> 4;
    float acc[6][4];
#pragma unroll
    for (int i = 0; i < 6; ++i)
#pragma unroll
        for (int j = 0; j < 4; ++j) acc[i][j] = 0.f;

    for (int ci0 = 0; ci0 < 305; ci0 += 16) {
        int ccn = min(16, 305 - ci0);
        __syncthreads();
        for (int idx = tid; idx < ccn * 3 * 66; idx += 192) {
            int cc = idx / 198;
            int rem = idx % 198;
            int r = rem / 66;
            int col = rem % 66;
            int cig = ci0 + cc;
            const float* src = (cig < 256) ? (xim + (size_t)cig * HW)
                                           : (cim + (size_t)(cig - 256) * HW);
            int hh = h + r - 1;
            int wcol = col - 1;
            rows[cc][r][col] =
                (hh >= 0 && hh < HH && wcol >= 0 && wcol < WW) ? src[hh * WW + wcol] : 0.f;
        }
        __syncthreads();
        for (int cc = 0; cc < ccn; ++cc) {
            const float* wbase = woT + (size_t)(ci0 + cc) * 9 * 72 + og * 6;
#pragma unroll
            for (int kh = 0; kh < 3; ++kh) {
                const float* rp = &rows[cc][kh][wg * 4];
                float4 i0 = *reinterpret_cast<const float4*>(rp);
                float iv[6] = {i0.x, i0.y, i0.z, i0.w, rp[4], rp[5]};
#pragma unroll
                for (int kw = 0; kw < 3; ++kw) {
                    const float* wr = wbase + (kh * 3 + kw) * 72;
                    float2 w0 = *reinterpret_cast<const float2*>(wr);
                    float2 w1 = *reinterpret_cast<const float2*>(wr + 2);
                    float2 w2 = *reinterpret_cast<const float2*>(wr + 4);
                    float wv[6] = {w0.x, w0.y, w1.x, w1.y, w2.x, w2.y};
#pragma unroll
                    for (int i = 0; i < 6; ++i)
#pragma unroll
                        for (int j = 0; j < 4; ++j) acc[i][j] += wv[i] * iv[j + kw];
                }
            }
        }
    }
    float* op = off + (size_t)z * 72 * HW + h * WW;
#pragma unroll
    for (int i = 0; i < 6; ++i) {
        int o = og * 6 + i;
#pragma unroll
        for (int j = 0; j < 4; ++j) op[(size_t)o * HW + wg * 4 + j] = acc[i][j];
    }
}

// ---------------- deformable conv (fp32 VALU, unchanged) ----------------
__global__ void __launch_bounds__(256, 2) deform_kernel(const float* __restrict__ in,
                                                        const float* __restrict__ off,
                                                        const float* __restrict__ wdefT,
                                                        float* __restrict__ feats) {
    __shared__ float v[256][64];
    int h = blockIdx.x, b = blockIdx.y, pair = blockIdx.z;
    int z = pair * 4 + b;
    const float* xim = in + (size_t)(b * GG + pair) * CC * HW;
    const float* offp = off + (size_t)z * 72 * HW;
    int tid = threadIdx.x;
    int lane = tid & 63;
    int g = tid >> 6;
    int wg = tid & 7;
    int og = tid >> 3;

    float acc[8][8];
#pragma unroll
    for (int i = 0; i < 8; ++i)
#pragma unroll
        for (int j = 0; j < 8; ++j) acc[i][j] = 0.f;

    for (int k = 0; k < 9; ++k) {
        {
            float oy = offp[(size_t)(g * 18 + k * 2 + 0) * HW + h * WW + lane];
            float ox = offp[(size_t)(g * 18 + k * 2 + 1) * HW + h * WW + lane];
            float py = (float)h + (float)(k / 3 - 1) + oy;
            float px = (float)lane + (float)(k % 3 - 1) + ox;
            float y0f = floorf(py), x0f = floorf(px);
            float fy = py - y0f, fx = px - x0f;
            int y0 = (int)y0f, x0 = (int)x0f;
            int y1 = y0 + 1, x1 = x0 + 1;
            bool vy0 = (y0 >= 0) && (y0 < HH);
            bool vy1 = (y1 >= 0) && (y1 < HH);
            bool vx0 = (x0 >= 0) && (x0 < WW);
            bool vx1 = (x1 >= 0) && (x1 < WW);
            float w00 = (1.f - fy) * (1.f - fx) * ((vy0 && vx0) ? 1.f : 0.f);
            float w01 = (1.f - fy) * fx * ((vy0 && vx1) ? 1.f : 0.f);
            float w10 = fy * (1.f - fx) * ((vy1 && vx0) ? 1.f : 0.f);
            float w11 = fy * fx * ((vy1 && vx1) ? 1.f : 0.f);
            int cy0 = min(max(y0, 0), HH - 1), cy1 = min(max(y1, 0), HH - 1);
            int cx0 = min(max(x0, 0), WW - 1), cx1 = min(max(x1, 0), WW - 1);
            int r0 = cy0 * WW, r1 = cy1 * WW;
            const float* xc = xim + (size_t)(g * 64) * HW;
#pragma unroll 4
            for (int cg = 0; cg < 64; ++cg) {
                const float* p = xc + (size_t)cg * HW;
                float s = w00 * p[r0 + cx0] + w01 * p[r0 + cx1] +
                          w10 * p[r1 + cx0] + w11 * p[r1 + cx1];
                v[g * 64 + cg][lane] = s;
            }
        }
        __syncthreads();
        const float* wk = wdefT + (size_t)k * 256 * 256;
        for (int c = 0; c < 256; ++c) {
            float4 v0 = *reinterpret_cast<const float4*>(&v[c][wg * 8]);
            float4 v1 = *reinterpret_cast<const float4*>(&v[c][wg * 8 + 4]);
            float vv[8] = {v0.x, v0.y, v0.z, v0.w, v1.x, v1.y, v1.z, v1.w};
            const float* wrow = wk + c * 256 + og * 8;
            float4 w0 = *reinterpret_cast<const float4*>(wrow);
            float4 w1 = *reinterpret_cast<const float4*>(wrow + 4);
            float wv[8] = {w0.x, w0.y, w0.z, w0.w, w1.x, w1.y, w1.z, w1.w};
#pragma unroll
            for (int i = 0; i < 8; ++i)
#pragma unroll
                for (int j = 0; j < 8; ++j) acc[i][j] += wv[i] * vv[j];
        }
        __syncthreads();
    }
    float* fout = feats + (size_t)z * 256 * HW + h * WW;
#pragma unroll
    for (int i = 0; i < 8; ++i) {
        int o = og * 8 + i;
#pragma unroll
        for (int j = 0; j < 8; ++j) fout[(size_t)o * HW + wg * 8 + j] = acc[i][j];
    }
}

// ---------------- FT build: feats(+y) fp32 [c][hw] -> FT bf16 [b][hw][1024] ----------------
__global__ void __launch_bounds__(256) ft_build(const float* __restrict__ in,
                                                const float* __restrict__ feats,
                                                ushort_t* __restrict__ FT) {
    __shared__ ushort_t tileT[64][72];
    int hw0 = blockIdx.x * 64;
    int ci0 = blockIdx.y * 64;
    int b = blockIdx.z;
    int t = threadIdx.x;
    int cil = t >> 2, q = t & 3;
    int cig = ci0 + cil;
    const float* src = (cig < 768)
        ? feats + ((size_t)((cig >> 8) * 4 + b) * 256 + (cig & 255)) * HW
        : in + ((size_t)(b * 4 + 3) * 256 + (size_t)(cig - 768)) * HW;
    const float* sp = src + hw0 + q * 16;
#pragma unroll
    for (int i = 0; i < 16; ++i) tileT[q * 16 + i][cil] = f2bf(sp[i]);
    __syncthreads();
    int hwl = t >> 2;
    const uint4* tp = reinterpret_cast<const uint4*>(&tileT[hwl][q * 16]);
    uint4* op = reinterpret_cast<uint4*>(&FT[((size_t)b * HW + hw0 + hwl) * 1024 + ci0 + q * 16]);
    op[0] = tp[0];
    op[1] = tp[1];
}

// ---------------- fusion conv via MFMA bf16 ----------------
__global__ void __launch_bounds__(256, 2) fusion_mfma(const ushort_t* __restrict__ FT,
                                                      const ushort_t* __restrict__ wmf,
                                                      float* __restrict__ out) {
    __shared__ ushort_t a_lds[64][40];
    __shared__ ushort_t b_lds[128][40];
    int o0 = blockIdx.x * 64;
    int n0 = blockIdx.y * 128;
    int b = blockIdx.z;
    int t = threadIdx.x;
    int wid = t >> 6;
    int lane = t & 63;
    int l15 = lane & 15;
    int kq = lane >> 4;
    int r2 = t >> 1, half = t & 1;
    int hwB = n0 + r2;
    int hB = hwB >> 6, wB = hwB & 63;
    const ushort_t* ftb = FT + (size_t)b * HW * 1024;

    f32x4 acc[4][2];
#pragma unroll
    for (int fm = 0; fm < 4; ++fm)
#pragma unroll
        for (int fn = 0; fn < 2; ++fn) acc[fm][fn] = (f32x4){0.f, 0.f, 0.f, 0.f};

    for (int kk = 0; kk < 288; ++kk) {
        int tap = kk >> 5;
        int ci0 = (kk & 31) << 5;
        int kh = tap / 3;
        int kw = tap - kh * 3;
        int hP = hB + kh - 1;
        int wP = wB + kw - 1;
        bool valid = (hP >= 0) && (hP < HH) && (wP >= 0) && (wP < WW);
        uint4 vb0 = make_uint4(0, 0, 0, 0), vb1 = make_uint4(0, 0, 0, 0);
        if (valid) {
            const uint4* gp = reinterpret_cast<const uint4*>(
                ftb + (size_t)(hP * WW + wP) * 1024 + ci0 + half * 16);
            vb0 = gp[0];
            vb1 = gp[1];
        }
        uint4 va0, va1;
        if (t < 128) {
            const uint4* ga = reinterpret_cast<const uint4*>(
                wmf + ((size_t)(tap * 256 + o0 + r2) << 10) + ci0 + half * 16);
            va0 = ga[0];
            va1 = ga[1];
        }
        __syncthreads();
        {
            uint4* bp = reinterpret_cast<uint4*>(&b_lds[r2][half * 16]);
            bp[0] = vb0;
            bp[1] = vb1;
            if (t < 128) {
                uint4* ap = reinterpret_cast<uint4*>(&a_lds[r2][half * 16]);
                ap[0] = va0;
                ap[1] = va1;
            }
        }
        __syncthreads();
        short8 af[4], bf[2];
#pragma unroll
        for (int fm = 0; fm < 4; ++fm)
            af[fm] = *reinterpret_cast<const short8*>(&a_lds[fm * 16 + l15][kq * 8]);
#pragma unroll
        for (int fn = 0; fn < 2; ++fn)
            bf[fn] = *reinterpret_cast<const short8*>(&b_lds[wid * 32 + fn * 16 + l15][kq * 8]);
#pragma unroll
        for (int fm = 0; fm < 4; ++fm)
#pragma unroll
            for (int fn = 0; fn < 2; ++fn)
                acc[fm][fn] = __builtin_amdgcn_mfma_f32_16x16x32_bf16(af[fm], bf[fn],
                                                                      acc[fm][fn], 0, 0, 0);
    }
    float* ob = out + ((size_t)b * 256 + o0) * HW + n0 + wid * 32;
#pragma unroll
    for (int fm = 0; fm < 4; ++fm)
#pragma unroll
        for (int fn = 0; fn < 2; ++fn)
#pragma unroll
            for (int e = 0; e < 4; ++e) {
                int o_l = fm * 16 + 4 * kq + e;
                ob[(size_t)o_l * HW + fn * 16 + l15] = acc[fm][fn][e];
            }
}

extern "C" void kernel_launch(void* const* d_in, const int* in_sizes, int n_in,
                              void* d_out, int out_size, void* d_ws, size_t ws_size,
                              hipStream_t stream) {
    const float* in   = (const float*)d_in[0];   // [16,256,64,64]
    const float* wOff = (const float*)d_in[1];   // [72,305,3,3]
    const float* wDef = (const float*)d_in[2];   // [256,256,3,3]
    const float* wFus = (const float*)d_in[3];   // [256,1024,3,3]
    float* out = (float*)d_out;                  // [4,256,64,64]
    char* base = (char*)d_ws;

    // FT (bf16, 33.5 MB) overlays corr (9.6 MB) + off (14.2 MB): both dead before ft_build.
    ushort_t* FT    = (ushort_t*)base;                          // 33,554,432 B
    float* corrB    = (float*)base;                             //  9,633,792 B
    float* offB     = (float*)(base + 9633792);                 // 14,155,776 B
    float* feats    = (float*)(base + 33554432);                // 50,331,648 B
    float* wdefT    = (float*)(base + 83886080);                //  2,359,296 B
    float* woT      = (float*)(base + 86245376);                //    790,560 B
    ushort_t* wfusMF = (ushort_t*)(base + 87035936);            //  4,718,592 B

    hipLaunchKernelGGL(transpose_wdef, dim3((256 * 256 * 9 + 255) / 256), dim3(256), 0, stream,
                       wDef, wdefT);
    hipLaunchKernelGGL(transpose_woff, dim3((72 * 305 * 9 + 255) / 256), dim3(256), 0, stream,
                       wOff, woT);
    hipLaunchKernelGGL(prep_wfus, dim3((9 * 256 * 1024 + 255) / 256), dim3(256), 0, stream,
                       wFus, wfusMF);
    hipLaunchKernelGGL(corr_kernel, dim3(64, 12), dim3(256), 0, stream, in, corrB);
    hipLaunchKernelGGL(offconv_kernel, dim3(64, 12), dim3(192), 0, stream,
                       in, corrB, woT, offB);
    hipLaunchKernelGGL(deform_kernel, dim3(64, 4, 3), dim3(256), 0, stream,
                       in, offB, wdefT, feats);
    hipLaunchKernelGGL(ft_build, dim3(64, 16, 4), dim3(256), 0, stream, in, feats, FT);
    hipLaunchKernelGGL(fusion_mfma, dim3(4, 32, 4), dim3(256), 0, stream, FT, wfusMF, out);
}

// Round 5
// 1465.154 us; speedup vs baseline: 4.6605x; 1.4890x over previous
//
#include <hip/hip_runtime.h>

#define HH 64
#define WW 64
#define HW 4096
#define CC 256
#define BB 4
#define GG 4
#define NPAIR 3

typedef __attribute__((ext_vector_type(8))) short short8;
typedef __attribute__((ext_vector_type(4))) float f32x4;
typedef unsigned short ushort_t;

__device__ inline ushort_t f2bf(float x) {
    unsigned int u = __float_as_uint(x);
    unsigned int r = (u + 0x7fffu + ((u >> 16) & 1u)) >> 16;
    return (ushort_t)r;
}

// ---------------- weight preps ----------------
// w_def [o][c][kh][kw] fp32 -> wdefMF[k][o][c] bf16 (MFMA A-operand layout)
__global__ void prep_wdef(const float* __restrict__ wd, ushort_t* __restrict__ wmf) {
    int idx = blockIdx.x * 256 + threadIdx.x;  // 9*256*256
    if (idx >= 9 * 256 * 256) return;
    int k = idx >> 16;
    int rem = idx & 65535;
    int o = rem >> 8;
    int c = rem & 255;
    wmf[idx] = f2bf(wd[((size_t)(o * 256 + c)) * 9 + k]);
}

// w_offset [72][305][9] -> wOffT[(ci*9+k)*72 + o]  (fp32)
__global__ void transpose_woff(const float* __restrict__ wo, float* __restrict__ woT) {
    int idx = blockIdx.x * 256 + threadIdx.x;  // 72*305*9
    if (idx >= 72 * 305 * 9) return;
    int o = idx / (305 * 9);
    int rem = idx % (305 * 9);
    woT[rem * 72 + o] = wo[idx];
}

// w_fusion [o][ci][3][3] fp32 -> wfusMF[k][o][ci] bf16
__global__ void prep_wfus(const float* __restrict__ wf, ushort_t* __restrict__ wmf) {
    int idx = blockIdx.x * 256 + threadIdx.x;  // 9*256*1024
    if (idx >= 9 * 256 * 1024) return;
    int k = idx / (256 * 1024);
    int rem = idx % (256 * 1024);
    int o = rem / 1024;
    int ci = rem % 1024;
    wmf[idx] = f2bf(wf[((size_t)o * 1024 + ci) * 9 + k]);
}

// ---------------- correlation (LDS-staged, 7-row window) ----------------
__global__ void __launch_bounds__(256, 2) corr_kernel(const float* __restrict__ in,
                                                      float* __restrict__ corr) {
    __shared__ float x1l[8][64];
    __shared__ float x2l[8][7][76];
    int h = blockIdx.x, z = blockIdx.y;
    int pair = z >> 2, b = z & 3;
    const float* x1 = in + (size_t)(b * GG + pair) * CC * HW + h * WW;
    const float* x2 = in + (size_t)(b * GG + 3) * CC * HW;
    int tid = threadIdx.x;
    int w = tid & 63;
    int dg = tid >> 6;

    float acc[2][7];
#pragma unroll
    for (int i = 0; i < 2; ++i)
#pragma unroll
        for (int j = 0; j < 7; ++j) acc[i][j] = 0.f;

    for (int c0 = 0; c0 < CC; c0 += 8) {
        __syncthreads();
#pragma unroll
        for (int idx = tid; idx < 512; idx += 256) {
            int cc = idx >> 6, ww = idx & 63;
            x1l[cc][ww] = x1[(size_t)(c0 + cc) * HW + ww];
        }
        for (int idx = tid; idx < 8 * 7 * 76; idx += 256) {
            int cc = idx / 532;
            int rem = idx - cc * 532;
            int r = rem / 76;
            int cl = rem - r * 76;
            int row = h + 2 * (r - 3);
            int col = cl - 6;
            float v = 0.f;
            if (row >= 0 && row < HH && col >= 0 && col < WW)
                v = x2[(size_t)(c0 + cc) * HW + row * WW + col];
            x2l[cc][r][cl] = v;
        }
        __syncthreads();
#pragma unroll
        for (int cc = 0; cc < 8; ++cc) {
            float x1v = x1l[cc][w];
#pragma unroll
            for (int i = 0; i < 2; ++i) {
                int di = dg * 2 + i;
                if (di < 7) {
#pragma unroll
                    for (int dj = 0; dj < 7; ++dj)
                        acc[i][dj] += x1v * x2l[cc][di][w + 2 * dj];
                }
            }
        }
    }
    float* cp = corr + (size_t)z * 49 * HW + h * WW + w;
#pragma unroll
    for (int i = 0; i < 2; ++i) {
        int di = dg * 2 + i;
        if (di < 7) {
#pragma unroll
            for (int dj = 0; dj < 7; ++dj)
                cp[(size_t)(di * 7 + dj) * HW] = acc[i][dj] * (1.f / 256.f);
        }
    }
}

// ---------------- offset conv (305 -> 72, 3x3, pad 1) ----------------
__global__ void __launch_bounds__(192, 2) offconv_kernel(const float* __restrict__ in,
                                                         const float* __restrict__ corr,
                                                         const float* __restrict__ woT,
                                                         float* __restrict__ off) {
    __shared__ float rows[16][3][68];
    int h = blockIdx.x, z = blockIdx.y;
    int pair = z >> 2, b = z & 3;
    const float* xim = in + (size_t)(b * GG + pair) * CC * HW;
    const float* cim = corr + (size_t)z * 49 * HW;
    int tid = threadIdx.x;
    int wg = tid & 15;
    int og = tid >> 4;
    float acc[6][4];
#pragma unroll
    for (int i = 0; i < 6; ++i)
#pragma unroll
        for (int j = 0; j < 4; ++j) acc[i][j] = 0.f;

    for (int ci0 = 0; ci0 < 305; ci0 += 16) {
        int ccn = min(16, 305 - ci0);
        __syncthreads();
        for (int idx = tid; idx < ccn * 3 * 66; idx += 192) {
            int cc = idx / 198;
            int rem = idx % 198;
            int r = rem / 66;
            int col = rem % 66;
            int cig = ci0 + cc;
            const float* src = (cig < 256) ? (xim + (size_t)cig * HW)
                                           : (cim + (size_t)(cig - 256) * HW);
            int hh = h + r - 1;
            int wcol = col - 1;
            rows[cc][r][col] =
                (hh >= 0 && hh < HH && wcol >= 0 && wcol < WW) ? src[hh * WW + wcol] : 0.f;
        }
        __syncthreads();
        for (int cc = 0; cc < ccn; ++cc) {
            const float* wbase = woT + (size_t)(ci0 + cc) * 9 * 72 + og * 6;
#pragma unroll
            for (int kh = 0; kh < 3; ++kh) {
                const float* rp = &rows[cc][kh][wg * 4];
                float4 i0 = *reinterpret_cast<const float4*>(rp);
                float iv[6] = {i0.x, i0.y, i0.z, i0.w, rp[4], rp[5]};
#pragma unroll
                for (int kw = 0; kw < 3; ++kw) {
                    const float* wr = wbase + (kh * 3 + kw) * 72;
                    float2 w0 = *reinterpret_cast<const float2*>(wr);
                    float2 w1 = *reinterpret_cast<const float2*>(wr + 2);
                    float2 w2 = *reinterpret_cast<const float2*>(wr + 4);
                    float wv[6] = {w0.x, w0.y, w1.x, w1.y, w2.x, w2.y};
#pragma unroll
                    for (int i = 0; i < 6; ++i)
#pragma unroll
                        for (int j = 0; j < 4; ++j) acc[i][j] += wv[i] * iv[j + kw];
                }
            }
        }
    }
    float* op = off + (size_t)z * 72 * HW + h * WW;
#pragma unroll
    for (int i = 0; i < 6; ++i) {
        int o = og * 6 + i;
#pragma unroll
        for (int j = 0; j < 4; ++j) op[(size_t)o * HW + wg * 4 + j] = acc[i][j];
    }
}

// ---------------- deformable conv via MFMA bf16 ----------------
// 1-D grid 768 (XCD-chunked: all h-rows of a (pair,b) image on one XCD).
// Per block (z,h): sample -> b_lds[w][c] bf16 (stride 264); 4 waves x
// (64o x 64w) MFMA; A-frags straight from L2-resident wdefMF[k][o][c].
// Epilogue: LDS transpose -> coalesced bf16 write directly into FT.
__global__ void __launch_bounds__(256, 3) deform_mfma(const float* __restrict__ in,
                                                      const float* __restrict__ off,
                                                      const ushort_t* __restrict__ wmf,
                                                      ushort_t* __restrict__ FT) {
    __shared__ ushort_t b_lds[64][264];
    // XCD-chunked swizzle: 768 = 8 XCDs x 96 contiguous slots
    int u = blockIdx.x & 7, v = blockIdx.x >> 3;
    int lin = u * 96 + v;
    int z = lin >> 6, h = lin & 63;
    int b = z & 3, pair = z >> 2;

    const float* xim = in + (size_t)(b * GG + pair) * CC * HW;
    const float* offp = off + (size_t)z * 72 * HW;
    int tid = threadIdx.x;
    int lane = tid & 63;   // sampling: w
    int g = tid >> 6;      // sampling: deform group / MFMA: wave id
    int l15 = tid & 15;
    int kq = (tid >> 4) & 3;

    f32x4 acc[4][4];
#pragma unroll
    for (int m = 0; m < 4; ++m)
#pragma unroll
        for (int n = 0; n < 4; ++n) acc[m][n] = (f32x4){0.f, 0.f, 0.f, 0.f};

    for (int k = 0; k < 9; ++k) {
        __syncthreads();
        // ---- sampling phase: thread (g, w=lane) samples 64 channels ----
        {
            float oy = offp[(size_t)(g * 18 + k * 2 + 0) * HW + h * WW + lane];
            float ox = offp[(size_t)(g * 18 + k * 2 + 1) * HW + h * WW + lane];
            float py = (float)h + (float)(k / 3 - 1) + oy;
            float px = (float)lane + (float)(k % 3 - 1) + ox;
            float y0f = floorf(py), x0f = floorf(px);
            float fy = py - y0f, fx = px - x0f;
            int y0 = (int)y0f, x0 = (int)x0f;
            int y1 = y0 + 1, x1 = x0 + 1;
            bool vy0 = (y0 >= 0) && (y0 < HH);
            bool vy1 = (y1 >= 0) && (y1 < HH);
            bool vx0 = (x0 >= 0) && (x0 < WW);
            bool vx1 = (x1 >= 0) && (x1 < WW);
            float w00 = (1.f - fy) * (1.f - fx) * ((vy0 && vx0) ? 1.f : 0.f);
            float w01 = (1.f - fy) * fx * ((vy0 && vx1) ? 1.f : 0.f);
            float w10 = fy * (1.f - fx) * ((vy1 && vx0) ? 1.f : 0.f);
            float w11 = fy * fx * ((vy1 && vx1) ? 1.f : 0.f);
            int cy0 = min(max(y0, 0), HH - 1), cy1 = min(max(y1, 0), HH - 1);
            int cx0 = min(max(x0, 0), WW - 1), cx1 = min(max(x1, 0), WW - 1);
            int r0 = cy0 * WW, r1 = cy1 * WW;
            const float* xc = xim + (size_t)(g * 64) * HW;
            for (int cg0 = 0; cg0 < 64; cg0 += 8) {
                unsigned pw[4];
#pragma unroll
                for (int q = 0; q < 4; ++q) {
                    const float* p0 = xc + (size_t)(cg0 + 2 * q) * HW;
                    const float* p1 = p0 + HW;
                    float s0 = w00 * p0[r0 + cx0] + w01 * p0[r0 + cx1] +
                               w10 * p0[r1 + cx0] + w11 * p0[r1 + cx1];
                    float s1 = w00 * p1[r0 + cx0] + w01 * p1[r0 + cx1] +
                               w10 * p1[r1 + cx0] + w11 * p1[r1 + cx1];
                    pw[q] = (unsigned)f2bf(s0) | ((unsigned)f2bf(s1) << 16);
                }
                uint4 vv = make_uint4(pw[0], pw[1], pw[2], pw[3]);
                *reinterpret_cast<uint4*>(&b_lds[lane][g * 64 + cg0]) = vv;
            }
        }
        __syncthreads();
        // ---- MFMA phase: wave g owns o-range g*64..+63, all 64 w ----
        const ushort_t* wkbase = wmf + (size_t)k * 65536 + (size_t)(g * 64) * 256;
#pragma unroll 1
        for (int cs = 0; cs < 8; ++cs) {
            int c0 = cs * 32;
            short8 bfr[4], afr[4];
#pragma unroll
            for (int n = 0; n < 4; ++n)
                bfr[n] = *reinterpret_cast<const short8*>(&b_lds[n * 16 + l15][c0 + kq * 8]);
#pragma unroll
            for (int m = 0; m < 4; ++m)
                afr[m] = *reinterpret_cast<const short8*>(
                    wkbase + (size_t)(m * 16 + l15) * 256 + c0 + kq * 8);
#pragma unroll
            for (int m = 0; m < 4; ++m)
#pragma unroll
                for (int n = 0; n < 4; ++n)
                    acc[m][n] = __builtin_amdgcn_mfma_f32_16x16x32_bf16(afr[m], bfr[n],
                                                                        acc[m][n], 0, 0, 0);
        }
    }
    // ---- epilogue: transpose via LDS, write bf16 directly into FT ----
    __syncthreads();
#pragma unroll
    for (int m = 0; m < 4; ++m)
#pragma unroll
        for (int n = 0; n < 4; ++n) {
            unsigned lo = (unsigned)f2bf(acc[m][n][0]) | ((unsigned)f2bf(acc[m][n][1]) << 16);
            unsigned hi = (unsigned)f2bf(acc[m][n][2]) | ((unsigned)f2bf(acc[m][n][3]) << 16);
            uint2 vv = make_uint2(lo, hi);
            *reinterpret_cast<uint2*>(&b_lds[n * 16 + l15][g * 64 + m * 16 + kq * 4]) = vv;
        }
    __syncthreads();
    int wout = tid >> 2, ch = tid & 3;
    ushort_t* dst = FT + ((size_t)b * HW + h * 64 + wout) * 1024 + pair * 256 + ch * 64;
    const ushort_t* srcl = &b_lds[wout][ch * 64];
#pragma unroll
    for (int i = 0; i < 8; ++i) {
        uint4 vv = *reinterpret_cast<const uint4*>(srcl + i * 8);
        *reinterpret_cast<uint4*>(dst + i * 8) = vv;
    }
}

// ---------------- FT build (y part only): in fp32 [c][hw] -> FT bf16 [b][hw][768+c] ----------------
__global__ void __launch_bounds__(256) ft_build_y(const float* __restrict__ in,
                                                  ushort_t* __restrict__ FT) {
    __shared__ ushort_t tileT[64][72];
    int hw0 = blockIdx.x * 64;
    int ct = blockIdx.y;
    int b = blockIdx.z;
    int t = threadIdx.x;
    int cil = t >> 2, q = t & 3;
    const float* sp = in + ((size_t)(b * 4 + 3) * 256 + ct * 64 + cil) * HW + hw0 + q * 16;
#pragma unroll
    for (int i = 0; i < 16; ++i) tileT[q * 16 + i][cil] = f2bf(sp[i]);
    __syncthreads();
    int hwl = t >> 2;
    const uint4* tp = reinterpret_cast<const uint4*>(&tileT[hwl][q * 16]);
    uint4* op = reinterpret_cast<uint4*>(
        &FT[((size_t)b * HW + hw0 + hwl) * 1024 + 768 + ct * 64 + q * 16]);
    op[0] = tp[0];
    op[1] = tp[1];
}

// ---------------- fusion conv via MFMA bf16 ----------------
__global__ void __launch_bounds__(256, 2) fusion_mfma(const ushort_t* __restrict__ FT,
                                                      const ushort_t* __restrict__ wmf,
                                                      float* __restrict__ out) {
    __shared__ ushort_t a_lds[64][40];
    __shared__ ushort_t b_lds[128][40];
    int o0 = blockIdx.x * 64;
    int n0 = blockIdx.y * 128;
    int b = blockIdx.z;
    int t = threadIdx.x;
    int wid = t >> 6;
    int lane = t & 63;
    int l15 = lane & 15;
    int kq = lane >> 4;
    int r2 = t >> 1, half = t & 1;
    int hwB = n0 + r2;
    int hB = hwB >> 6, wB = hwB & 63;
    const ushort_t* ftb = FT + (size_t)b * HW * 1024;

    f32x4 acc[4][2];
#pragma unroll
    for (int fm = 0; fm < 4; ++fm)
#pragma unroll
        for (int fn = 0; fn < 2; ++fn) acc[fm][fn] = (f32x4){0.f, 0.f, 0.f, 0.f};

    for (int kk = 0; kk < 288; ++kk) {
        int tap = kk >> 5;
        int ci0 = (kk & 31) << 5;
        int kh = tap / 3;
        int kw = tap - kh * 3;
        int hP = hB + kh - 1;
        int wP = wB + kw - 1;
        bool valid = (hP >= 0) && (hP < HH) && (wP >= 0) && (wP < WW);
        uint4 vb0 = make_uint4(0, 0, 0, 0), vb1 = make_uint4(0, 0, 0, 0);
        if (valid) {
            const uint4* gp = reinterpret_cast<const uint4*>(
                ftb + (size_t)(hP * WW + wP) * 1024 + ci0 + half * 16);
            vb0 = gp[0];
            vb1 = gp[1];
        }
        uint4 va0, va1;
        if (t < 128) {
            const uint4* ga = reinterpret_cast<const uint4*>(
                wmf + ((size_t)(tap * 256 + o0 + r2) << 10) + ci0 + half * 16);
            va0 = ga[0];
            va1 = ga[1];
        }
        __syncthreads();
        {
            uint4* bp = reinterpret_cast<uint4*>(&b_lds[r2][half * 16]);
            bp[0] = vb0;
            bp[1] = vb1;
            if (t < 128) {
                uint4* ap = reinterpret_cast<uint4*>(&a_lds[r2][half * 16]);
                ap[0] = va0;
                ap[1] = va1;
            }
        }
        __syncthreads();
        short8 af[4], bf[2];
#pragma unroll
        for (int fm = 0; fm < 4; ++fm)
            af[fm] = *reinterpret_cast<const short8*>(&a_lds[fm * 16 + l15][kq * 8]);
#pragma unroll
        for (int fn = 0; fn < 2; ++fn)
            bf[fn] = *reinterpret_cast<const short8*>(&b_lds[wid * 32 + fn * 16 + l15][kq * 8]);
#pragma unroll
        for (int fm = 0; fm < 4; ++fm)
#pragma unroll
            for (int fn = 0; fn < 2; ++fn)
                acc[fm][fn] = __builtin_amdgcn_mfma_f32_16x16x32_bf16(af[fm], bf[fn],
                                                                      acc[fm][fn], 0, 0, 0);
    }
    float* ob = out + ((size_t)b * 256 + o0) * HW + n0 + wid * 32;
#pragma unroll
    for (int fm = 0; fm < 4; ++fm)
#pragma unroll
        for (int fn = 0; fn < 2; ++fn)
#pragma unroll
            for (int e = 0; e < 4; ++e) {
                int o_l = fm * 16 + 4 * kq + e;
                ob[(size_t)o_l * HW + fn * 16 + l15] = acc[fm][fn][e];
            }
}

extern "C" void kernel_launch(void* const* d_in, const int* in_sizes, int n_in,
                              void* d_out, int out_size, void* d_ws, size_t ws_size,
                              hipStream_t stream) {
    const float* in   = (const float*)d_in[0];   // [16,256,64,64]
    const float* wOff = (const float*)d_in[1];   // [72,305,3,3]
    const float* wDef = (const float*)d_in[2];   // [256,256,3,3]
    const float* wFus = (const float*)d_in[3];   // [256,1024,3,3]
    float* out = (float*)d_out;                  // [4,256,64,64]
    char* base = (char*)d_ws;

    // Layout: FT bf16 [4][4096][1024] @0 (33.5 MB) overlays corrB (dead after
    // offconv). offB moved OUTSIDE FT range (deform reads off while writing FT).
    ushort_t* FT     = (ushort_t*)base;                 // 33,554,432 B
    float* corrB     = (float*)base;                    //  9,633,792 B (dead before FT writes)
    float* offB      = (float*)(base + 33554432);       // 14,155,776 B
    ushort_t* wdefMF = (ushort_t*)(base + 47710208);    //  1,179,648 B
    float* woT       = (float*)(base + 48889856);       //    790,560 B
    ushort_t* wfusMF = (ushort_t*)(base + 49680416);    //  4,718,592 B  (end 54.4 MB)

    hipLaunchKernelGGL(prep_wdef, dim3((9 * 256 * 256 + 255) / 256), dim3(256), 0, stream,
                       wDef, wdefMF);
    hipLaunchKernelGGL(transpose_woff, dim3((72 * 305 * 9 + 255) / 256), dim3(256), 0, stream,
                       wOff, woT);
    hipLaunchKernelGGL(prep_wfus, dim3((9 * 256 * 1024 + 255) / 256), dim3(256), 0, stream,
                       wFus, wfusMF);
    hipLaunchKernelGGL(corr_kernel, dim3(64, 12), dim3(256), 0, stream, in, corrB);
    hipLaunchKernelGGL(offconv_kernel, dim3(64, 12), dim3(192), 0, stream,
                       in, corrB, woT, offB);
    // ft_build_y AFTER offconv: its FT writes land inside the (now dead) corr region.
    hipLaunchKernelGGL(ft_build_y, dim3(64, 4, 4), dim3(256), 0, stream, in, FT);
    hipLaunchKernelGGL(deform_mfma, dim3(768), dim3(256), 0, stream, in, offB, wdefMF, FT);
    hipLaunchKernelGGL(fusion_mfma, dim3(4, 32, 4), dim3(256), 0, stream, FT, wfusMF, out);
}

// Round 7
// 967.591 us; speedup vs baseline: 7.0571x; 1.5142x over previous
//
#include <hip/hip_runtime.h>

#define HH 64
#define WW 64
#define HW 4096
#define CC 256
#define BB 4
#define GG 4
#define NPAIR 3

typedef __attribute__((ext_vector_type(8))) short short8;
typedef __attribute__((ext_vector_type(4))) float f32x4;
typedef unsigned short ushort_t;

__device__ inline ushort_t f2bf(float x) {
    unsigned int u = __float_as_uint(x);
    unsigned int r = (u + 0x7fffu + ((u >> 16) & 1u)) >> 16;
    return (ushort_t)r;
}

// ---------------- weight preps ----------------
// w_def [o][c][kh][kw] fp32 -> wdefMF[k][o][c] bf16 (MFMA A-operand layout)
__global__ void prep_wdef(const float* __restrict__ wd, ushort_t* __restrict__ wmf) {
    int idx = blockIdx.x * 256 + threadIdx.x;  // 9*256*256
    if (idx >= 9 * 256 * 256) return;
    int k = idx >> 16;
    int rem = idx & 65535;
    int o = rem >> 8;
    int c = rem & 255;
    wmf[idx] = f2bf(wd[((size_t)(o * 256 + c)) * 9 + k]);
}

// w_offset [72][305][9] fp32 -> woffMF[k][80][320] bf16, zero-padded
__global__ void prep_woff(const float* __restrict__ wo, ushort_t* __restrict__ wmf) {
    int idx = blockIdx.x * 256 + threadIdx.x;  // 9*80*320 = 230400
    if (idx >= 9 * 80 * 320) return;
    int k = idx / (80 * 320);
    int rem = idx % (80 * 320);
    int o = rem / 320;
    int ci = rem % 320;
    wmf[idx] = (o < 72 && ci < 305) ? f2bf(wo[((size_t)o * 305 + ci) * 9 + k]) : (ushort_t)0;
}

// w_fusion [o][ci][3][3] fp32 -> wfusMF[k][o][ci] bf16
__global__ void prep_wfus(const float* __restrict__ wf, ushort_t* __restrict__ wmf) {
    int idx = blockIdx.x * 256 + threadIdx.x;  // 9*256*1024
    if (idx >= 9 * 256 * 1024) return;
    int k = idx / (256 * 1024);
    int rem = idx % (256 * 1024);
    int o = rem / 1024;
    int ci = rem % 1024;
    wmf[idx] = f2bf(wf[((size_t)o * 1024 + ci) * 9 + k]);
}

// ---------------- XT build (x part): in fp32 [c][hw] -> XT bf16 [z][hw][320] cols 0..255 ----------------
__global__ void __launch_bounds__(256) xt_build(const float* __restrict__ in,
                                                ushort_t* __restrict__ XT) {
    __shared__ ushort_t tileT[64][72];
    int hw0 = blockIdx.x * 64;
    int ct = blockIdx.y;
    int z = blockIdx.z;
    int pair = z >> 2, b = z & 3;
    int t = threadIdx.x;
    int cil = t >> 2, q = t & 3;
    const float* sp = in + ((size_t)(b * 4 + pair) * 256 + ct * 64 + cil) * HW + hw0 + q * 16;
#pragma unroll
    for (int i = 0; i < 16; ++i) tileT[q * 16 + i][cil] = f2bf(sp[i]);
    __syncthreads();
    int hwl = t >> 2;
    const uint4* tp = reinterpret_cast<const uint4*>(&tileT[hwl][q * 16]);
    uint4* op = reinterpret_cast<uint4*>(
        &XT[((size_t)z * HW + hw0 + hwl) * 320 + ct * 64 + q * 16]);
    op[0] = tp[0];
    op[1] = tp[1];
}

// ---------------- correlation (LDS-staged) -> writes bf16 into XT cols 256..319 ----------------
__global__ void __launch_bounds__(256, 2) corr_kernel(const float* __restrict__ in,
                                                      ushort_t* __restrict__ XT) {
    __shared__ float x1l[8][64];
    __shared__ float x2l[8][7][76];
    int h = blockIdx.x, z = blockIdx.y;
    int pair = z >> 2, b = z & 3;
    const float* x1 = in + (size_t)(b * GG + pair) * CC * HW + h * WW;
    const float* x2 = in + (size_t)(b * GG + 3) * CC * HW;
    int tid = threadIdx.x;
    int w = tid & 63;
    int dg = tid >> 6;

    float acc[2][7];
#pragma unroll
    for (int i = 0; i < 2; ++i)
#pragma unroll
        for (int j = 0; j < 7; ++j) acc[i][j] = 0.f;

    for (int c0 = 0; c0 < CC; c0 += 8) {
        __syncthreads();
#pragma unroll
        for (int idx = tid; idx < 512; idx += 256) {
            int cc = idx >> 6, ww = idx & 63;
            x1l[cc][ww] = x1[(size_t)(c0 + cc) * HW + ww];
        }
        for (int idx = tid; idx < 8 * 7 * 76; idx += 256) {
            int cc = idx / 532;
            int rem = idx - cc * 532;
            int r = rem / 76;
            int cl = rem - r * 76;
            int row = h + 2 * (r - 3);
            int col = cl - 6;
            float v = 0.f;
            if (row >= 0 && row < HH && col >= 0 && col < WW)
                v = x2[(size_t)(c0 + cc) * HW + row * WW + col];
            x2l[cc][r][cl] = v;
        }
        __syncthreads();
#pragma unroll
        for (int cc = 0; cc < 8; ++cc) {
            float x1v = x1l[cc][w];
#pragma unroll
            for (int i = 0; i < 2; ++i) {
                int di = dg * 2 + i;
                if (di < 7) {
#pragma unroll
                    for (int dj = 0; dj < 7; ++dj)
                        acc[i][dj] += x1v * x2l[cc][di][w + 2 * dj];
                }
            }
        }
    }
    ushort_t* xrow = XT + ((size_t)z * HW + h * WW + w) * 320;
#pragma unroll
    for (int i = 0; i < 2; ++i) {
        int di = dg * 2 + i;
        if (di < 7) {
#pragma unroll
            for (int dj = 0; dj < 7; ++dj)
                xrow[256 + di * 7 + dj] = f2bf(acc[i][dj] * (1.f / 256.f));
        }
    }
    if (dg == 3) {  // zero the ci pad 305..319
#pragma unroll
        for (int p = 0; p < 15; ++p) xrow[305 + p] = 0;
    }
}

// ---------------- offset conv via MFMA bf16 (80x128 tile, taps as row shifts) ----------------
// grid (32 n-tiles, 12 z), block 256 = 4 waves x (80 o x 32 hw)
__global__ void __launch_bounds__(256, 2) offconv_mfma(const ushort_t* __restrict__ XT,
                                                       const ushort_t* __restrict__ wmf,
                                                       float* __restrict__ off) {
    __shared__ ushort_t a_lds[80][40];
    __shared__ ushort_t b_lds[128][40];
    int n0 = blockIdx.x * 128;
    int z = blockIdx.y;
    int t = threadIdx.x;
    int wid = t >> 6;
    int lane = t & 63;
    int l15 = lane & 15;
    int kq = lane >> 4;
    int r2 = t >> 1, half = t & 1;
    int hwB = n0 + r2;
    int hB = hwB >> 6, wB = hwB & 63;
    const ushort_t* xtb = XT + (size_t)z * HW * 320;

    f32x4 acc[5][2];
#pragma unroll
    for (int m = 0; m < 5; ++m)
#pragma unroll
        for (int n = 0; n < 2; ++n) acc[m][n] = (f32x4){0.f, 0.f, 0.f, 0.f};

    for (int tap = 0; tap < 9; ++tap) {
        int kh = tap / 3;
        int kw = tap - kh * 3;
        int hP = hB + kh - 1;
        int wP = wB + kw - 1;
        bool valid = (hP >= 0) && (hP < HH) && (wP >= 0) && (wP < WW);
        const ushort_t* brow = xtb + (size_t)(hP * WW + wP) * 320;
#pragma unroll 1
        for (int cs = 0; cs < 10; ++cs) {
            int ci0 = cs * 32;
            // FIX (r6 bug): stage the FULL 16-ushort half (2 uint4s), not 1.
            uint4 vb0 = make_uint4(0, 0, 0, 0), vb1 = make_uint4(0, 0, 0, 0);
            if (valid) {
                const uint4* gp = reinterpret_cast<const uint4*>(brow + ci0 + half * 16);
                vb0 = gp[0];
                vb1 = gp[1];
            }
            uint4 va0, va1;
            if (t < 160) {
                const uint4* ga = reinterpret_cast<const uint4*>(
                    wmf + ((size_t)tap * 80 + r2) * 320 + ci0 + half * 16);
                va0 = ga[0];
                va1 = ga[1];
            }
            __syncthreads();
            {
                uint4* bp = reinterpret_cast<uint4*>(&b_lds[r2][half * 16]);
                bp[0] = vb0;
                bp[1] = vb1;
                if (t < 160) {
                    uint4* ap = reinterpret_cast<uint4*>(&a_lds[r2][half * 16]);
                    ap[0] = va0;
                    ap[1] = va1;
                }
            }
            __syncthreads();
            short8 af[5], bf[2];
#pragma unroll
            for (int m = 0; m < 5; ++m)
                af[m] = *reinterpret_cast<const short8*>(&a_lds[m * 16 + l15][kq * 8]);
#pragma unroll
            for (int n = 0; n < 2; ++n)
                bf[n] = *reinterpret_cast<const short8*>(&b_lds[wid * 32 + n * 16 + l15][kq * 8]);
#pragma unroll
            for (int m = 0; m < 5; ++m)
#pragma unroll
                for (int n = 0; n < 2; ++n)
                    acc[m][n] = __builtin_amdgcn_mfma_f32_16x16x32_bf16(af[m], bf[n],
                                                                        acc[m][n], 0, 0, 0);
        }
    }
    float* ob = off + (size_t)z * 72 * HW + n0 + wid * 32;
#pragma unroll
    for (int m = 0; m < 5; ++m)
#pragma unroll
        for (int n = 0; n < 2; ++n)
#pragma unroll
            for (int e = 0; e < 4; ++e) {
                int o_l = m * 16 + kq * 4 + e;
                if (o_l < 72) ob[(size_t)o_l * HW + n * 16 + l15] = acc[m][n][e];
            }
}

// ---------------- deformable conv via MFMA bf16 ----------------
__global__ void __launch_bounds__(256, 3) deform_mfma(const float* __restrict__ in,
                                                      const float* __restrict__ off,
                                                      const ushort_t* __restrict__ wmf,
                                                      ushort_t* __restrict__ FT) {
    __shared__ ushort_t b_lds[64][264];
    int u = blockIdx.x & 7, v = blockIdx.x >> 3;
    int lin = u * 96 + v;
    int z = lin >> 6, h = lin & 63;
    int b = z & 3, pair = z >> 2;

    const float* xim = in + (size_t)(b * GG + pair) * CC * HW;
    const float* offp = off + (size_t)z * 72 * HW;
    int tid = threadIdx.x;
    int lane = tid & 63;
    int g = tid >> 6;
    int l15 = tid & 15;
    int kq = (tid >> 4) & 3;

    f32x4 acc[4][4];
#pragma unroll
    for (int m = 0; m < 4; ++m)
#pragma unroll
        for (int n = 0; n < 4; ++n) acc[m][n] = (f32x4){0.f, 0.f, 0.f, 0.f};

    for (int k = 0; k < 9; ++k) {
        __syncthreads();
        {
            float oy = offp[(size_t)(g * 18 + k * 2 + 0) * HW + h * WW + lane];
            float ox = offp[(size_t)(g * 18 + k * 2 + 1) * HW + h * WW + lane];
            float py = (float)h + (float)(k / 3 - 1) + oy;
            float px = (float)lane + (float)(k % 3 - 1) + ox;
            float y0f = floorf(py), x0f = floorf(px);
            float fy = py - y0f, fx = px - x0f;
            int y0 = (int)y0f, x0 = (int)x0f;
            int y1 = y0 + 1, x1 = x0 + 1;
            bool vy0 = (y0 >= 0) && (y0 < HH);
            bool vy1 = (y1 >= 0) && (y1 < HH);
            bool vx0 = (x0 >= 0) && (x0 < WW);
            bool vx1 = (x1 >= 0) && (x1 < WW);
            float w00 = (1.f - fy) * (1.f - fx) * ((vy0 && vx0) ? 1.f : 0.f);
            float w01 = (1.f - fy) * fx * ((vy0 && vx1) ? 1.f : 0.f);
            float w10 = fy * (1.f - fx) * ((vy1 && vx0) ? 1.f : 0.f);
            float w11 = fy * fx * ((vy1 && vx1) ? 1.f : 0.f);
            int cy0 = min(max(y0, 0), HH - 1), cy1 = min(max(y1, 0), HH - 1);
            int cx0 = min(max(x0, 0), WW - 1), cx1 = min(max(x1, 0), WW - 1);
            int r0 = cy0 * WW, r1 = cy1 * WW;
            const float* xc = xim + (size_t)(g * 64) * HW;
            for (int cg0 = 0; cg0 < 64; cg0 += 8) {
                unsigned pw[4];
#pragma unroll
                for (int q = 0; q < 4; ++q) {
                    const float* p0 = xc + (size_t)(cg0 + 2 * q) * HW;
                    const float* p1 = p0 + HW;
                    float s0 = w00 * p0[r0 + cx0] + w01 * p0[r0 + cx1] +
                               w10 * p0[r1 + cx0] + w11 * p0[r1 + cx1];
                    float s1 = w00 * p1[r0 + cx0] + w01 * p1[r0 + cx1] +
                               w10 * p1[r1 + cx0] + w11 * p1[r1 + cx1];
                    pw[q] = (unsigned)f2bf(s0) | ((unsigned)f2bf(s1) << 16);
                }
                uint4 vv = make_uint4(pw[0], pw[1], pw[2], pw[3]);
                *reinterpret_cast<uint4*>(&b_lds[lane][g * 64 + cg0]) = vv;
            }
        }
        __syncthreads();
        const ushort_t* wkbase = wmf + (size_t)k * 65536 + (size_t)(g * 64) * 256;
#pragma unroll 1
        for (int cs = 0; cs < 8; ++cs) {
            int c0 = cs * 32;
            short8 bfr[4], afr[4];
#pragma unroll
            for (int n = 0; n < 4; ++n)
                bfr[n] = *reinterpret_cast<const short8*>(&b_lds[n * 16 + l15][c0 + kq * 8]);
#pragma unroll
            for (int m = 0; m < 4; ++m)
                afr[m] = *reinterpret_cast<const short8*>(
                    wkbase + (size_t)(m * 16 + l15) * 256 + c0 + kq * 8);
#pragma unroll
            for (int m = 0; m < 4; ++m)
#pragma unroll
                for (int n = 0; n < 4; ++n)
                    acc[m][n] = __builtin_amdgcn_mfma_f32_16x16x32_bf16(afr[m], bfr[n],
                                                                        acc[m][n], 0, 0, 0);
        }
    }
    __syncthreads();
#pragma unroll
    for (int m = 0; m < 4; ++m)
#pragma unroll
        for (int n = 0; n < 4; ++n) {
            unsigned lo = (unsigned)f2bf(acc[m][n][0]) | ((unsigned)f2bf(acc[m][n][1]) << 16);
            unsigned hi = (unsigned)f2bf(acc[m][n][2]) | ((unsigned)f2bf(acc[m][n][3]) << 16);
            uint2 vv = make_uint2(lo, hi);
            *reinterpret_cast<uint2*>(&b_lds[n * 16 + l15][g * 64 + m * 16 + kq * 4]) = vv;
        }
    __syncthreads();
    int wout = tid >> 2, ch = tid & 3;
    ushort_t* dst = FT + ((size_t)b * HW + h * 64 + wout) * 1024 + pair * 256 + ch * 64;
    const ushort_t* srcl = &b_lds[wout][ch * 64];
#pragma unroll
    for (int i = 0; i < 8; ++i) {
        uint4 vv = *reinterpret_cast<const uint4*>(srcl + i * 8);
        *reinterpret_cast<uint4*>(dst + i * 8) = vv;
    }
}

// ---------------- FT build (y part): in fp32 [c][hw] -> FT bf16 [b][hw][768+c] ----------------
__global__ void __launch_bounds__(256) ft_build_y(const float* __restrict__ in,
                                                  ushort_t* __restrict__ FT) {
    __shared__ ushort_t tileT[64][72];
    int hw0 = blockIdx.x * 64;
    int ct = blockIdx.y;
    int b = blockIdx.z;
    int t = threadIdx.x;
    int cil = t >> 2, q = t & 3;
    const float* sp = in + ((size_t)(b * 4 + 3) * 256 + ct * 64 + cil) * HW + hw0 + q * 16;
#pragma unroll
    for (int i = 0; i < 16; ++i) tileT[q * 16 + i][cil] = f2bf(sp[i]);
    __syncthreads();
    int hwl = t >> 2;
    const uint4* tp = reinterpret_cast<const uint4*>(&tileT[hwl][q * 16]);
    uint4* op = reinterpret_cast<uint4*>(
        &FT[((size_t)b * HW + hw0 + hwl) * 1024 + 768 + ct * 64 + q * 16]);
    op[0] = tp[0];
    op[1] = tp[1];
}

// ---------------- fusion conv via MFMA bf16 ----------------
__global__ void __launch_bounds__(256, 2) fusion_mfma(const ushort_t* __restrict__ FT,
                                                      const ushort_t* __restrict__ wmf,
                                                      float* __restrict__ out) {
    __shared__ ushort_t a_lds[64][40];
    __shared__ ushort_t b_lds[128][40];
    int o0 = blockIdx.x * 64;
    int n0 = blockIdx.y * 128;
    int b = blockIdx.z;
    int t = threadIdx.x;
    int wid = t >> 6;
    int lane = t & 63;
    int l15 = lane & 15;
    int kq = lane >> 4;
    int r2 = t >> 1, half = t & 1;
    int hwB = n0 + r2;
    int hB = hwB >> 6, wB = hwB & 63;
    const ushort_t* ftb = FT + (size_t)b * HW * 1024;

    f32x4 acc[4][2];
#pragma unroll
    for (int fm = 0; fm < 4; ++fm)
#pragma unroll
        for (int fn = 0; fn < 2; ++fn) acc[fm][fn] = (f32x4){0.f, 0.f, 0.f, 0.f};

    for (int kk = 0; kk < 288; ++kk) {
        int tap = kk >> 5;
        int ci0 = (kk & 31) << 5;
        int kh = tap / 3;
        int kw = tap - kh * 3;
        int hP = hB + kh - 1;
        int wP = wB + kw - 1;
        bool valid = (hP >= 0) && (hP < HH) && (wP >= 0) && (wP < WW);
        uint4 vb0 = make_uint4(0, 0, 0, 0), vb1 = make_uint4(0, 0, 0, 0);
        if (valid) {
            const uint4* gp = reinterpret_cast<const uint4*>(
                ftb + (size_t)(hP * WW + wP) * 1024 + ci0 + half * 16);
            vb0 = gp[0];
            vb1 = gp[1];
        }
        uint4 va0, va1;
        if (t < 128) {
            const uint4* ga = reinterpret_cast<const uint4*>(
                wmf + ((size_t)(tap * 256 + o0 + r2) << 10) + ci0 + half * 16);
            va0 = ga[0];
            va1 = ga[1];
        }
        __syncthreads();
        {
            uint4* bp = reinterpret_cast<uint4*>(&b_lds[r2][half * 16]);
            bp[0] = vb0;
            bp[1] = vb1;
            if (t < 128) {
                uint4* ap = reinterpret_cast<uint4*>(&a_lds[r2][half * 16]);
                ap[0] = va0;
                ap[1] = va1;
            }
        }
        __syncthreads();
        short8 af[4], bf[2];
#pragma unroll
        for (int fm = 0; fm < 4; ++fm)
            af[fm] = *reinterpret_cast<const short8*>(&a_lds[fm * 16 + l15][kq * 8]);
#pragma unroll
        for (int fn = 0; fn < 2; ++fn)
            bf[fn] = *reinterpret_cast<const short8*>(&b_lds[wid * 32 + fn * 16 + l15][kq * 8]);
#pragma unroll
        for (int fm = 0; fm < 4; ++fm)
#pragma unroll
            for (int fn = 0; fn < 2; ++fn)
                acc[fm][fn] = __builtin_amdgcn_mfma_f32_16x16x32_bf16(af[fm], bf[fn],
                                                                      acc[fm][fn], 0, 0, 0);
    }
    float* ob = out + ((size_t)b * 256 + o0) * HW + n0 + wid * 32;
#pragma unroll
    for (int fm = 0; fm < 4; ++fm)
#pragma unroll
        for (int fn = 0; fn < 2; ++fn)
#pragma unroll
            for (int e = 0; e < 4; ++e) {
                int o_l = fm * 16 + 4 * kq + e;
                ob[(size_t)o_l * HW + fn * 16 + l15] = acc[fm][fn][e];
            }
}

extern "C" void kernel_launch(void* const* d_in, const int* in_sizes, int n_in,
                              void* d_out, int out_size, void* d_ws, size_t ws_size,
                              hipStream_t stream) {
    const float* in   = (const float*)d_in[0];   // [16,256,64,64]
    const float* wOff = (const float*)d_in[1];   // [72,305,3,3]
    const float* wDef = (const float*)d_in[2];   // [256,256,3,3]
    const float* wFus = (const float*)d_in[3];   // [256,1024,3,3]
    float* out = (float*)d_out;                  // [4,256,64,64]
    char* base = (char*)d_ws;

    // Region at base is time-shared: XT bf16 [12][4096][320] (31.5 MB) lives
    // until offconv_mfma; FT bf16 [4][4096][1024] (33.5 MB) is written after.
    ushort_t* XT     = (ushort_t*)base;                 // 31,457,280 B
    ushort_t* FT     = (ushort_t*)base;                 // 33,554,432 B
    float* offB      = (float*)(base + 33554432);       // 14,155,776 B
    ushort_t* wdefMF = (ushort_t*)(base + 47710208);    //  1,179,648 B
    ushort_t* woffMF = (ushort_t*)(base + 48889856);    //    460,800 B
    ushort_t* wfusMF = (ushort_t*)(base + 49350656);    //  4,718,592 B  (end 54.1 MB)

    hipLaunchKernelGGL(prep_wdef, dim3((9 * 256 * 256 + 255) / 256), dim3(256), 0, stream,
                       wDef, wdefMF);
    hipLaunchKernelGGL(prep_woff, dim3((9 * 80 * 320 + 255) / 256), dim3(256), 0, stream,
                       wOff, woffMF);
    hipLaunchKernelGGL(prep_wfus, dim3((9 * 256 * 1024 + 255) / 256), dim3(256), 0, stream,
                       wFus, wfusMF);
    hipLaunchKernelGGL(xt_build, dim3(64, 4, 12), dim3(256), 0, stream, in, XT);
    hipLaunchKernelGGL(corr_kernel, dim3(64, 12), dim3(256), 0, stream, in, XT);
    hipLaunchKernelGGL(offconv_mfma, dim3(32, 12), dim3(256), 0, stream, XT, woffMF, offB);
    // XT dead from here; FT region reuses it.
    hipLaunchKernelGGL(ft_build_y, dim3(64, 4, 4), dim3(256), 0, stream, in, FT);
    hipLaunchKernelGGL(deform_mfma, dim3(768), dim3(256), 0, stream, in, offB, wdefMF, FT);
    hipLaunchKernelGGL(fusion_mfma, dim3(4, 32, 4), dim3(256), 0, stream, FT, wfusMF, out);
}

// Round 8
// 717.788 us; speedup vs baseline: 9.5131x; 1.3480x over previous
//
#include <hip/hip_runtime.h>

#define HH 64
#define WW 64
#define HW 4096
#define CC 256
#define BB 4
#define GG 4
#define NPAIR 3

typedef __attribute__((ext_vector_type(8))) short short8;
typedef __attribute__((ext_vector_type(4))) float f32x4;
typedef unsigned short ushort_t;

__device__ inline ushort_t f2bf(float x) {
    unsigned int u = __float_as_uint(x);
    unsigned int r = (u + 0x7fffu + ((u >> 16) & 1u)) >> 16;
    return (ushort_t)r;
}
__device__ inline float bflo(unsigned u) { return __uint_as_float(u << 16); }
__device__ inline float bfhi(unsigned u) { return __uint_as_float(u & 0xffff0000u); }

// ---------------- weight preps ----------------
__global__ void prep_wdef(const float* __restrict__ wd, ushort_t* __restrict__ wmf) {
    int idx = blockIdx.x * 256 + threadIdx.x;  // 9*256*256
    if (idx >= 9 * 256 * 256) return;
    int k = idx >> 16;
    int rem = idx & 65535;
    int o = rem >> 8;
    int c = rem & 255;
    wmf[idx] = f2bf(wd[((size_t)(o * 256 + c)) * 9 + k]);
}

__global__ void prep_woff(const float* __restrict__ wo, ushort_t* __restrict__ wmf) {
    int idx = blockIdx.x * 256 + threadIdx.x;  // 9*80*320
    if (idx >= 9 * 80 * 320) return;
    int k = idx / (80 * 320);
    int rem = idx % (80 * 320);
    int o = rem / 320;
    int ci = rem % 320;
    wmf[idx] = (o < 72 && ci < 305) ? f2bf(wo[((size_t)o * 305 + ci) * 9 + k]) : (ushort_t)0;
}

__global__ void prep_wfus(const float* __restrict__ wf, ushort_t* __restrict__ wmf) {
    int idx = blockIdx.x * 256 + threadIdx.x;  // 9*256*1024
    if (idx >= 9 * 256 * 1024) return;
    int k = idx / (256 * 1024);
    int rem = idx % (256 * 1024);
    int o = rem / 1024;
    int ci = rem % 1024;
    wmf[idx] = f2bf(wf[((size_t)o * 1024 + ci) * 9 + k]);
}

// ---------------- XT build: in fp32 [c][hw] -> XT bf16 [z][hw][320] cols 0..255 ----------------
__global__ void __launch_bounds__(256) xt_build(const float* __restrict__ in,
                                                ushort_t* __restrict__ XT) {
    __shared__ ushort_t tileT[64][72];
    int hw0 = blockIdx.x * 64;
    int ct = blockIdx.y;
    int z = blockIdx.z;
    int pair = z >> 2, b = z & 3;
    int t = threadIdx.x;
    int cil = t >> 2, q = t & 3;
    const float* sp = in + ((size_t)(b * 4 + pair) * 256 + ct * 64 + cil) * HW + hw0 + q * 16;
#pragma unroll
    for (int i = 0; i < 16; ++i) tileT[q * 16 + i][cil] = f2bf(sp[i]);
    __syncthreads();
    int hwl = t >> 2;
    const uint4* tp = reinterpret_cast<const uint4*>(&tileT[hwl][q * 16]);
    uint4* op = reinterpret_cast<uint4*>(
        &XT[((size_t)z * HW + hw0 + hwl) * 320 + ct * 64 + q * 16]);
    op[0] = tp[0];
    op[1] = tp[1];
}

// ---------------- correlation -> bf16 into XT cols 256..319 ----------------
__global__ void __launch_bounds__(256, 2) corr_kernel(const float* __restrict__ in,
                                                      ushort_t* __restrict__ XT) {
    __shared__ float x1l[8][64];
    __shared__ float x2l[8][7][76];
    int h = blockIdx.x, z = blockIdx.y;
    int pair = z >> 2, b = z & 3;
    const float* x1 = in + (size_t)(b * GG + pair) * CC * HW + h * WW;
    const float* x2 = in + (size_t)(b * GG + 3) * CC * HW;
    int tid = threadIdx.x;
    int w = tid & 63;
    int dg = tid >> 6;

    float acc[2][7];
#pragma unroll
    for (int i = 0; i < 2; ++i)
#pragma unroll
        for (int j = 0; j < 7; ++j) acc[i][j] = 0.f;

    for (int c0 = 0; c0 < CC; c0 += 8) {
        __syncthreads();
#pragma unroll
        for (int idx = tid; idx < 512; idx += 256) {
            int cc = idx >> 6, ww = idx & 63;
            x1l[cc][ww] = x1[(size_t)(c0 + cc) * HW + ww];
        }
        for (int idx = tid; idx < 8 * 7 * 76; idx += 256) {
            int cc = idx / 532;
            int rem = idx - cc * 532;
            int r = rem / 76;
            int cl = rem - r * 76;
            int row = h + 2 * (r - 3);
            int col = cl - 6;
            float v = 0.f;
            if (row >= 0 && row < HH && col >= 0 && col < WW)
                v = x2[(size_t)(c0 + cc) * HW + row * WW + col];
            x2l[cc][r][cl] = v;
        }
        __syncthreads();
#pragma unroll
        for (int cc = 0; cc < 8; ++cc) {
            float x1v = x1l[cc][w];
#pragma unroll
            for (int i = 0; i < 2; ++i) {
                int di = dg * 2 + i;
                if (di < 7) {
#pragma unroll
                    for (int dj = 0; dj < 7; ++dj)
                        acc[i][dj] += x1v * x2l[cc][di][w + 2 * dj];
                }
            }
        }
    }
    ushort_t* xrow = XT + ((size_t)z * HW + h * WW + w) * 320;
#pragma unroll
    for (int i = 0; i < 2; ++i) {
        int di = dg * 2 + i;
        if (di < 7) {
#pragma unroll
            for (int dj = 0; dj < 7; ++dj)
                xrow[256 + di * 7 + dj] = f2bf(acc[i][dj] * (1.f / 256.f));
        }
    }
    if (dg == 3) {
#pragma unroll
        for (int p = 0; p < 15; ++p) xrow[305 + p] = 0;
    }
}

// ---------------- offset conv via MFMA bf16 ----------------
__global__ void __launch_bounds__(256, 2) offconv_mfma(const ushort_t* __restrict__ XT,
                                                       const ushort_t* __restrict__ wmf,
                                                       float* __restrict__ off) {
    __shared__ ushort_t a_lds[80][40];
    __shared__ ushort_t b_lds[128][40];
    int n0 = blockIdx.x * 128;
    int z = blockIdx.y;
    int t = threadIdx.x;
    int wid = t >> 6;
    int lane = t & 63;
    int l15 = lane & 15;
    int kq = lane >> 4;
    int r2 = t >> 1, half = t & 1;
    int hwB = n0 + r2;
    int hB = hwB >> 6, wB = hwB & 63;
    const ushort_t* xtb = XT + (size_t)z * HW * 320;

    f32x4 acc[5][2];
#pragma unroll
    for (int m = 0; m < 5; ++m)
#pragma unroll
        for (int n = 0; n < 2; ++n) acc[m][n] = (f32x4){0.f, 0.f, 0.f, 0.f};

    for (int tap = 0; tap < 9; ++tap) {
        int kh = tap / 3;
        int kw = tap - kh * 3;
        int hP = hB + kh - 1;
        int wP = wB + kw - 1;
        bool valid = (hP >= 0) && (hP < HH) && (wP >= 0) && (wP < WW);
        const ushort_t* brow = xtb + (size_t)(hP * WW + wP) * 320;
#pragma unroll 1
        for (int cs = 0; cs < 10; ++cs) {
            int ci0 = cs * 32;
            uint4 vb0 = make_uint4(0, 0, 0, 0), vb1 = make_uint4(0, 0, 0, 0);
            if (valid) {
                const uint4* gp = reinterpret_cast<const uint4*>(brow + ci0 + half * 16);
                vb0 = gp[0];
                vb1 = gp[1];
            }
            uint4 va0, va1;
            if (t < 160) {
                const uint4* ga = reinterpret_cast<const uint4*>(
                    wmf + ((size_t)tap * 80 + r2) * 320 + ci0 + half * 16);
                va0 = ga[0];
                va1 = ga[1];
            }
            __syncthreads();
            {
                uint4* bp = reinterpret_cast<uint4*>(&b_lds[r2][half * 16]);
                bp[0] = vb0;
                bp[1] = vb1;
                if (t < 160) {
                    uint4* ap = reinterpret_cast<uint4*>(&a_lds[r2][half * 16]);
                    ap[0] = va0;
                    ap[1] = va1;
                }
            }
            __syncthreads();
            short8 af[5], bf[2];
#pragma unroll
            for (int m = 0; m < 5; ++m)
                af[m] = *reinterpret_cast<const short8*>(&a_lds[m * 16 + l15][kq * 8]);
#pragma unroll
            for (int n = 0; n < 2; ++n)
                bf[n] = *reinterpret_cast<const short8*>(&b_lds[wid * 32 + n * 16 + l15][kq * 8]);
#pragma unroll
            for (int m = 0; m < 5; ++m)
#pragma unroll
                for (int n = 0; n < 2; ++n)
                    acc[m][n] = __builtin_amdgcn_mfma_f32_16x16x32_bf16(af[m], bf[n],
                                                                        acc[m][n], 0, 0, 0);
        }
    }
    float* ob = off + (size_t)z * 72 * HW + n0 + wid * 32;
#pragma unroll
    for (int m = 0; m < 5; ++m)
#pragma unroll
        for (int n = 0; n < 2; ++n)
#pragma unroll
            for (int e = 0; e < 4; ++e) {
                int o_l = m * 16 + kq * 4 + e;
                if (o_l < 72) ob[(size_t)o_l * HW + n * 16 + l15] = acc[m][n][e];
            }
}

// ---------------- deformable conv via MFMA bf16 (samples from XT, hw-major bf16) ----------------
__global__ void __launch_bounds__(256, 3) deform_mfma(const ushort_t* __restrict__ XT,
                                                      const float* __restrict__ off,
                                                      const ushort_t* __restrict__ wmf,
                                                      ushort_t* __restrict__ FT) {
    __shared__ ushort_t b_lds[64][264];
    int u = blockIdx.x & 7, v = blockIdx.x >> 3;
    int lin = u * 96 + v;
    int z = lin >> 6, h = lin & 63;
    int b = z & 3, pair = z >> 2;

    const ushort_t* xtz = XT + (size_t)z * HW * 320;
    const float* offp = off + (size_t)z * 72 * HW;
    int tid = threadIdx.x;
    int lane = tid & 63;
    int g = tid >> 6;
    int l15 = tid & 15;
    int kq = (tid >> 4) & 3;

    f32x4 acc[4][4];
#pragma unroll
    for (int m = 0; m < 4; ++m)
#pragma unroll
        for (int n = 0; n < 4; ++n) acc[m][n] = (f32x4){0.f, 0.f, 0.f, 0.f};

    for (int k = 0; k < 9; ++k) {
        __syncthreads();
        // ---- sampling: thread (g, w=lane), 64 channels from XT (contiguous per pos) ----
        {
            float oy = offp[(size_t)(g * 18 + k * 2 + 0) * HW + h * WW + lane];
            float ox = offp[(size_t)(g * 18 + k * 2 + 1) * HW + h * WW + lane];
            float py = (float)h + (float)(k / 3 - 1) + oy;
            float px = (float)lane + (float)(k % 3 - 1) + ox;
            float y0f = floorf(py), x0f = floorf(px);
            float fy = py - y0f, fx = px - x0f;
            int y0 = (int)y0f, x0 = (int)x0f;
            int y1 = y0 + 1, x1 = x0 + 1;
            bool vy0 = (y0 >= 0) && (y0 < HH);
            bool vy1 = (y1 >= 0) && (y1 < HH);
            bool vx0 = (x0 >= 0) && (x0 < WW);
            bool vx1 = (x1 >= 0) && (x1 < WW);
            float w00 = (1.f - fy) * (1.f - fx) * ((vy0 && vx0) ? 1.f : 0.f);
            float w01 = (1.f - fy) * fx * ((vy0 && vx1) ? 1.f : 0.f);
            float w10 = fy * (1.f - fx) * ((vy1 && vx0) ? 1.f : 0.f);
            float w11 = fy * fx * ((vy1 && vx1) ? 1.f : 0.f);
            int cy0 = min(max(y0, 0), HH - 1), cy1 = min(max(y1, 0), HH - 1);
            int cx0 = min(max(x0, 0), WW - 1), cx1 = min(max(x1, 0), WW - 1);
            const ushort_t* p00 = xtz + (size_t)(cy0 * WW + cx0) * 320 + g * 64;
            const ushort_t* p01 = xtz + (size_t)(cy0 * WW + cx1) * 320 + g * 64;
            const ushort_t* p10 = xtz + (size_t)(cy1 * WW + cx0) * 320 + g * 64;
            const ushort_t* p11 = xtz + (size_t)(cy1 * WW + cx1) * 320 + g * 64;
#pragma unroll
            for (int c0 = 0; c0 < 64; c0 += 8) {
                uint4 a00 = *reinterpret_cast<const uint4*>(p00 + c0);
                uint4 a01 = *reinterpret_cast<const uint4*>(p01 + c0);
                uint4 a10 = *reinterpret_cast<const uint4*>(p10 + c0);
                uint4 a11 = *reinterpret_cast<const uint4*>(p11 + c0);
                unsigned pw[4];
                const unsigned* u00 = &a00.x;
                const unsigned* u01 = &a01.x;
                const unsigned* u10 = &a10.x;
                const unsigned* u11 = &a11.x;
#pragma unroll
                for (int q = 0; q < 4; ++q) {
                    float s0 = w00 * bflo(u00[q]) + w01 * bflo(u01[q]) +
                               w10 * bflo(u10[q]) + w11 * bflo(u11[q]);
                    float s1 = w00 * bfhi(u00[q]) + w01 * bfhi(u01[q]) +
                               w10 * bfhi(u10[q]) + w11 * bfhi(u11[q]);
                    pw[q] = (unsigned)f2bf(s0) | ((unsigned)f2bf(s1) << 16);
                }
                *reinterpret_cast<uint4*>(&b_lds[lane][g * 64 + c0]) =
                    make_uint4(pw[0], pw[1], pw[2], pw[3]);
            }
        }
        __syncthreads();
        const ushort_t* wkbase = wmf + (size_t)k * 65536 + (size_t)(g * 64) * 256;
#pragma unroll 1
        for (int cs = 0; cs < 8; ++cs) {
            int c0 = cs * 32;
            short8 bfr[4], afr[4];
#pragma unroll
            for (int n = 0; n < 4; ++n)
                bfr[n] = *reinterpret_cast<const short8*>(&b_lds[n * 16 + l15][c0 + kq * 8]);
#pragma unroll
            for (int m = 0; m < 4; ++m)
                afr[m] = *reinterpret_cast<const short8*>(
                    wkbase + (size_t)(m * 16 + l15) * 256 + c0 + kq * 8);
#pragma unroll
            for (int m = 0; m < 4; ++m)
#pragma unroll
                for (int n = 0; n < 4; ++n)
                    acc[m][n] = __builtin_amdgcn_mfma_f32_16x16x32_bf16(afr[m], bfr[n],
                                                                        acc[m][n], 0, 0, 0);
        }
    }
    __syncthreads();
#pragma unroll
    for (int m = 0; m < 4; ++m)
#pragma unroll
        for (int n = 0; n < 4; ++n) {
            unsigned lo = (unsigned)f2bf(acc[m][n][0]) | ((unsigned)f2bf(acc[m][n][1]) << 16);
            unsigned hi = (unsigned)f2bf(acc[m][n][2]) | ((unsigned)f2bf(acc[m][n][3]) << 16);
            uint2 vv = make_uint2(lo, hi);
            *reinterpret_cast<uint2*>(&b_lds[n * 16 + l15][g * 64 + m * 16 + kq * 4]) = vv;
        }
    __syncthreads();
    int wout = tid >> 2, ch = tid & 3;
    ushort_t* dst = FT + ((size_t)b * HW + h * 64 + wout) * 1024 + pair * 256 + ch * 64;
    const ushort_t* srcl = &b_lds[wout][ch * 64];
#pragma unroll
    for (int i = 0; i < 8; ++i) {
        uint4 vv = *reinterpret_cast<const uint4*>(srcl + i * 8);
        *reinterpret_cast<uint4*>(dst + i * 8) = vv;
    }
}

// ---------------- FT build (y part) ----------------
__global__ void __launch_bounds__(256) ft_build_y(const float* __restrict__ in,
                                                  ushort_t* __restrict__ FT) {
    __shared__ ushort_t tileT[64][72];
    int hw0 = blockIdx.x * 64;
    int ct = blockIdx.y;
    int b = blockIdx.z;
    int t = threadIdx.x;
    int cil = t >> 2, q = t & 3;
    const float* sp = in + ((size_t)(b * 4 + 3) * 256 + ct * 64 + cil) * HW + hw0 + q * 16;
#pragma unroll
    for (int i = 0; i < 16; ++i) tileT[q * 16 + i][cil] = f2bf(sp[i]);
    __syncthreads();
    int hwl = t >> 2;
    const uint4* tp = reinterpret_cast<const uint4*>(&tileT[hwl][q * 16]);
    uint4* op = reinterpret_cast<uint4*>(
        &FT[((size_t)b * HW + hw0 + hwl) * 1024 + 768 + ct * 64 + q * 16]);
    op[0] = tp[0];
    op[1] = tp[1];
}

// ---------------- fusion conv via MFMA bf16 ----------------
__global__ void __launch_bounds__(256, 2) fusion_mfma(const ushort_t* __restrict__ FT,
                                                      const ushort_t* __restrict__ wmf,
                                                      float* __restrict__ out) {
    __shared__ ushort_t a_lds[64][40];
    __shared__ ushort_t b_lds[128][40];
    int o0 = blockIdx.x * 64;
    int n0 = blockIdx.y * 128;
    int b = blockIdx.z;
    int t = threadIdx.x;
    int wid = t >> 6;
    int lane = t & 63;
    int l15 = lane & 15;
    int kq = lane >> 4;
    int r2 = t >> 1, half = t & 1;
    int hwB = n0 + r2;
    int hB = hwB >> 6, wB = hwB & 63;
    const ushort_t* ftb = FT + (size_t)b * HW * 1024;

    f32x4 acc[4][2];
#pragma unroll
    for (int fm = 0; fm < 4; ++fm)
#pragma unroll
        for (int fn = 0; fn < 2; ++fn) acc[fm][fn] = (f32x4){0.f, 0.f, 0.f, 0.f};

    for (int kk = 0; kk < 288; ++kk) {
        int tap = kk >> 5;
        int ci0 = (kk & 31) << 5;
        int kh = tap / 3;
        int kw = tap - kh * 3;
        int hP = hB + kh - 1;
        int wP = wB + kw - 1;
        bool valid = (hP >= 0) && (hP < HH) && (wP >= 0) && (wP < WW);
        uint4 vb0 = make_uint4(0, 0, 0, 0), vb1 = make_uint4(0, 0, 0, 0);
        if (valid) {
            const uint4* gp = reinterpret_cast<const uint4*>(
                ftb + (size_t)(hP * WW + wP) * 1024 + ci0 + half * 16);
            vb0 = gp[0];
            vb1 = gp[1];
        }
        uint4 va0, va1;
        if (t < 128) {
            const uint4* ga = reinterpret_cast<const uint4*>(
                wmf + ((size_t)(tap * 256 + o0 + r2) << 10) + ci0 + half * 16);
            va0 = ga[0];
            va1 = ga[1];
        }
        __syncthreads();
        {
            uint4* bp = reinterpret_cast<uint4*>(&b_lds[r2][half * 16]);
            bp[0] = vb0;
            bp[1] = vb1;
            if (t < 128) {
                uint4* ap = reinterpret_cast<uint4*>(&a_lds[r2][half * 16]);
                ap[0] = va0;
                ap[1] = va1;
            }
        }
        __syncthreads();
        short8 af[4], bf[2];
#pragma unroll
        for (int fm = 0; fm < 4; ++fm)
            af[fm] = *reinterpret_cast<const short8*>(&a_lds[fm * 16 + l15][kq * 8]);
#pragma unroll
        for (int fn = 0; fn < 2; ++fn)
            bf[fn] = *reinterpret_cast<const short8*>(&b_lds[wid * 32 + fn * 16 + l15][kq * 8]);
#pragma unroll
        for (int fm = 0; fm < 4; ++fm)
#pragma unroll
            for (int fn = 0; fn < 2; ++fn)
                acc[fm][fn] = __builtin_amdgcn_mfma_f32_16x16x32_bf16(af[fm], bf[fn],
                                                                      acc[fm][fn], 0, 0, 0);
    }
    float* ob = out + ((size_t)b * 256 + o0) * HW + n0 + wid * 32;
#pragma unroll
    for (int fm = 0; fm < 4; ++fm)
#pragma unroll
        for (int fn = 0; fn < 2; ++fn)
#pragma unroll
            for (int e = 0; e < 4; ++e) {
                int o_l = fm * 16 + 4 * kq + e;
                ob[(size_t)o_l * HW + fn * 16 + l15] = acc[fm][fn][e];
            }
}

extern "C" void kernel_launch(void* const* d_in, const int* in_sizes, int n_in,
                              void* d_out, int out_size, void* d_ws, size_t ws_size,
                              hipStream_t stream) {
    const float* in   = (const float*)d_in[0];   // [16,256,64,64]
    const float* wOff = (const float*)d_in[1];   // [72,305,3,3]
    const float* wDef = (const float*)d_in[2];   // [256,256,3,3]
    const float* wFus = (const float*)d_in[3];   // [256,1024,3,3]
    float* out = (float*)d_out;                  // [4,256,64,64]
    char* base = (char*)d_ws;

    // XT kept alive through deform (it samples from XT); FT no longer overlays it.
    ushort_t* XT     = (ushort_t*)base;                 // 31,457,280 B
    ushort_t* FT     = (ushort_t*)(base + 31457280);    // 33,554,432 B -> 65,011,712
    float* offB      = (float*)(base + 65011712);       // 14,155,776 B -> 79,167,488
    ushort_t* wdefMF = (ushort_t*)(base + 79167488);    //  1,179,648 B -> 80,347,136
    ushort_t* woffMF = (ushort_t*)(base + 80347136);    //    460,800 B -> 80,807,936
    ushort_t* wfusMF = (ushort_t*)(base + 80807936);    //  4,718,592 B -> 85,526,528

    hipLaunchKernelGGL(prep_wdef, dim3((9 * 256 * 256 + 255) / 256), dim3(256), 0, stream,
                       wDef, wdefMF);
    hipLaunchKernelGGL(prep_woff, dim3((9 * 80 * 320 + 255) / 256), dim3(256), 0, stream,
                       wOff, woffMF);
    hipLaunchKernelGGL(prep_wfus, dim3((9 * 256 * 1024 + 255) / 256), dim3(256), 0, stream,
                       wFus, wfusMF);
    hipLaunchKernelGGL(xt_build, dim3(64, 4, 12), dim3(256), 0, stream, in, XT);
    hipLaunchKernelGGL(corr_kernel, dim3(64, 12), dim3(256), 0, stream, in, XT);
    hipLaunchKernelGGL(offconv_mfma, dim3(32, 12), dim3(256), 0, stream, XT, woffMF, offB);
    hipLaunchKernelGGL(ft_build_y, dim3(64, 4, 4), dim3(256), 0, stream, in, FT);
    hipLaunchKernelGGL(deform_mfma, dim3(768), dim3(256), 0, stream, XT, offB, wdefMF, FT);
    hipLaunchKernelGGL(fusion_mfma, dim3(4, 32, 4), dim3(256), 0, stream, FT, wfusMF, out);
}

// Round 9
// 642.785 us; speedup vs baseline: 10.6231x; 1.1167x over previous
//
#include <hip/hip_runtime.h>

#define HH 64
#define WW 64
#define HW 4096
#define CC 256
#define BB 4
#define GG 4
#define NPAIR 3

typedef __attribute__((ext_vector_type(8))) short short8;
typedef __attribute__((ext_vector_type(4))) float f32x4;
typedef unsigned short ushort_t;

__device__ inline ushort_t f2bf(float x) {
    unsigned int u = __float_as_uint(x);
    unsigned int r = (u + 0x7fffu + ((u >> 16) & 1u)) >> 16;
    return (ushort_t)r;
}
__device__ inline float bflo(unsigned u) { return __uint_as_float(u << 16); }
__device__ inline float bfhi(unsigned u) { return __uint_as_float(u & 0xffff0000u); }

// ---------------- weight preps ----------------
__global__ void prep_wdef(const float* __restrict__ wd, ushort_t* __restrict__ wmf) {
    int idx = blockIdx.x * 256 + threadIdx.x;  // 9*256*256
    if (idx >= 9 * 256 * 256) return;
    int k = idx >> 16;
    int rem = idx & 65535;
    int o = rem >> 8;
    int c = rem & 255;
    wmf[idx] = f2bf(wd[((size_t)(o * 256 + c)) * 9 + k]);
}

__global__ void prep_woff(const float* __restrict__ wo, ushort_t* __restrict__ wmf) {
    int idx = blockIdx.x * 256 + threadIdx.x;  // 9*80*320
    if (idx >= 9 * 80 * 320) return;
    int k = idx / (80 * 320);
    int rem = idx % (80 * 320);
    int o = rem / 320;
    int ci = rem % 320;
    wmf[idx] = (o < 72 && ci < 305) ? f2bf(wo[((size_t)o * 305 + ci) * 9 + k]) : (ushort_t)0;
}

__global__ void prep_wfus(const float* __restrict__ wf, ushort_t* __restrict__ wmf) {
    int idx = blockIdx.x * 256 + threadIdx.x;  // 9*256*1024
    if (idx >= 9 * 256 * 1024) return;
    int k = idx / (256 * 1024);
    int rem = idx % (256 * 1024);
    int o = rem / 1024;
    int ci = rem % 1024;
    wmf[idx] = f2bf(wf[((size_t)o * 1024 + ci) * 9 + k]);
}

// ---------------- XT build: in fp32 [c][hw] -> XT bf16 [z][hw][320] cols 0..255 ----------------
__global__ void __launch_bounds__(256) xt_build(const float* __restrict__ in,
                                                ushort_t* __restrict__ XT) {
    __shared__ ushort_t tileT[64][72];
    int hw0 = blockIdx.x * 64;
    int ct = blockIdx.y;
    int z = blockIdx.z;
    int pair = z >> 2, b = z & 3;
    int t = threadIdx.x;
    int cil = t >> 2, q = t & 3;
    const float* sp = in + ((size_t)(b * 4 + pair) * 256 + ct * 64 + cil) * HW + hw0 + q * 16;
#pragma unroll
    for (int i = 0; i < 16; ++i) tileT[q * 16 + i][cil] = f2bf(sp[i]);
    __syncthreads();
    int hwl = t >> 2;
    const uint4* tp = reinterpret_cast<const uint4*>(&tileT[hwl][q * 16]);
    uint4* op = reinterpret_cast<uint4*>(
        &XT[((size_t)z * HW + hw0 + hwl) * 320 + ct * 64 + q * 16]);
    op[0] = tp[0];
    op[1] = tp[1];
}

// ---------------- correlation partials (channel-split x4) ----------------
// grid (64 h, 12 z, 4 cg), block 256 = 64 w x 4 dg; 8 chans/chunk, 8 chunks.
// Writes fp32 partials P[cg][z][d][hw] (unscaled).
__global__ void __launch_bounds__(256, 8) corr_partial(const float* __restrict__ in,
                                                       float* __restrict__ P) {
    __shared__ float x1l[8][64];
    __shared__ float x2l[8][7][76];
    int h = blockIdx.x, z = blockIdx.y, cg = blockIdx.z;
    int pair = z >> 2, b = z & 3;
    const float* x1 = in + (size_t)(b * GG + pair) * CC * HW + h * WW;
    const float* x2 = in + (size_t)(b * GG + 3) * CC * HW;
    int tid = threadIdx.x;
    int w = tid & 63;
    int dg = tid >> 6;

    float acc[2][7];
#pragma unroll
    for (int i = 0; i < 2; ++i)
#pragma unroll
        for (int j = 0; j < 7; ++j) acc[i][j] = 0.f;

    for (int c0 = cg * 64; c0 < cg * 64 + 64; c0 += 8) {
        __syncthreads();
#pragma unroll
        for (int idx = tid; idx < 512; idx += 256) {
            int cc = idx >> 6, ww = idx & 63;
            x1l[cc][ww] = x1[(size_t)(c0 + cc) * HW + ww];
        }
        for (int idx = tid; idx < 8 * 7 * 76; idx += 256) {
            int cc = idx / 532;
            int rem = idx - cc * 532;
            int r = rem / 76;
            int cl = rem - r * 76;
            int row = h + 2 * (r - 3);
            int col = cl - 6;
            float v = 0.f;
            if (row >= 0 && row < HH && col >= 0 && col < WW)
                v = x2[(size_t)(c0 + cc) * HW + row * WW + col];
            x2l[cc][r][cl] = v;
        }
        __syncthreads();
#pragma unroll
        for (int cc = 0; cc < 8; ++cc) {
            float x1v = x1l[cc][w];
#pragma unroll
            for (int i = 0; i < 2; ++i) {
                int di = dg * 2 + i;
                if (di < 7) {
#pragma unroll
                    for (int dj = 0; dj < 7; ++dj)
                        acc[i][dj] += x1v * x2l[cc][di][w + 2 * dj];
                }
            }
        }
    }
    float* pp = P + ((size_t)(cg * 12 + z) * 49) * HW + h * WW + w;
#pragma unroll
    for (int i = 0; i < 2; ++i) {
        int di = dg * 2 + i;
        if (di < 7) {
#pragma unroll
            for (int dj = 0; dj < 7; ++dj)
                pp[(size_t)(di * 7 + dj) * HW] = acc[i][dj];
        }
    }
}

// ---------------- corr reduce: sum 4 partials -> bf16 XT cols 256..319 ----------------
__global__ void __launch_bounds__(256) corr_reduce(const float* __restrict__ P,
                                                   ushort_t* __restrict__ XT) {
    int h = blockIdx.x, z = blockIdx.y;
    int tid = threadIdx.x;
    int w = tid & 63;
    int dg = tid >> 6;
    const size_t cgs = (size_t)12 * 49 * HW;
    ushort_t* xrow = XT + ((size_t)z * HW + h * WW + w) * 320;
#pragma unroll
    for (int i = 0; i < 2; ++i) {
        int di = dg * 2 + i;
        if (di < 7) {
#pragma unroll
            for (int dj = 0; dj < 7; ++dj) {
                int d = di * 7 + dj;
                const float* pp = P + ((size_t)z * 49 + d) * HW + h * WW + w;
                float s = pp[0] + pp[cgs] + pp[2 * cgs] + pp[3 * cgs];
                xrow[256 + d] = f2bf(s * (1.f / 256.f));
            }
        }
    }
    if (dg == 3) {
#pragma unroll
        for (int p = 0; p < 15; ++p) xrow[305 + p] = 0;
    }
}

// ---------------- offset conv via MFMA bf16 ----------------
__global__ void __launch_bounds__(256, 2) offconv_mfma(const ushort_t* __restrict__ XT,
                                                       const ushort_t* __restrict__ wmf,
                                                       float* __restrict__ off) {
    __shared__ ushort_t a_lds[80][40];
    __shared__ ushort_t b_lds[128][40];
    int n0 = blockIdx.x * 128;
    int z = blockIdx.y;
    int t = threadIdx.x;
    int wid = t >> 6;
    int lane = t & 63;
    int l15 = lane & 15;
    int kq = lane >> 4;
    int r2 = t >> 1, half = t & 1;
    int hwB = n0 + r2;
    int hB = hwB >> 6, wB = hwB & 63;
    const ushort_t* xtb = XT + (size_t)z * HW * 320;

    f32x4 acc[5][2];
#pragma unroll
    for (int m = 0; m < 5; ++m)
#pragma unroll
        for (int n = 0; n < 2; ++n) acc[m][n] = (f32x4){0.f, 0.f, 0.f, 0.f};

    for (int tap = 0; tap < 9; ++tap) {
        int kh = tap / 3;
        int kw = tap - kh * 3;
        int hP = hB + kh - 1;
        int wP = wB + kw - 1;
        bool valid = (hP >= 0) && (hP < HH) && (wP >= 0) && (wP < WW);
        const ushort_t* brow = xtb + (size_t)(hP * WW + wP) * 320;
#pragma unroll 1
        for (int cs = 0; cs < 10; ++cs) {
            int ci0 = cs * 32;
            uint4 vb0 = make_uint4(0, 0, 0, 0), vb1 = make_uint4(0, 0, 0, 0);
            if (valid) {
                const uint4* gp = reinterpret_cast<const uint4*>(brow + ci0 + half * 16);
                vb0 = gp[0];
                vb1 = gp[1];
            }
            uint4 va0, va1;
            if (t < 160) {
                const uint4* ga = reinterpret_cast<const uint4*>(
                    wmf + ((size_t)tap * 80 + r2) * 320 + ci0 + half * 16);
                va0 = ga[0];
                va1 = ga[1];
            }
            __syncthreads();
            {
                uint4* bp = reinterpret_cast<uint4*>(&b_lds[r2][half * 16]);
                bp[0] = vb0;
                bp[1] = vb1;
                if (t < 160) {
                    uint4* ap = reinterpret_cast<uint4*>(&a_lds[r2][half * 16]);
                    ap[0] = va0;
                    ap[1] = va1;
                }
            }
            __syncthreads();
            short8 af[5], bf[2];
#pragma unroll
            for (int m = 0; m < 5; ++m)
                af[m] = *reinterpret_cast<const short8*>(&a_lds[m * 16 + l15][kq * 8]);
#pragma unroll
            for (int n = 0; n < 2; ++n)
                bf[n] = *reinterpret_cast<const short8*>(&b_lds[wid * 32 + n * 16 + l15][kq * 8]);
#pragma unroll
            for (int m = 0; m < 5; ++m)
#pragma unroll
                for (int n = 0; n < 2; ++n)
                    acc[m][n] = __builtin_amdgcn_mfma_f32_16x16x32_bf16(af[m], bf[n],
                                                                        acc[m][n], 0, 0, 0);
        }
    }
    float* ob = off + (size_t)z * 72 * HW + n0 + wid * 32;
#pragma unroll
    for (int m = 0; m < 5; ++m)
#pragma unroll
        for (int n = 0; n < 2; ++n)
#pragma unroll
            for (int e = 0; e < 4; ++e) {
                int o_l = m * 16 + kq * 4 + e;
                if (o_l < 72) ob[(size_t)o_l * HW + n * 16 + l15] = acc[m][n][e];
            }
}

// ---------------- deformable conv via MFMA bf16 (samples from XT) ----------------
__global__ void __launch_bounds__(256, 3) deform_mfma(const ushort_t* __restrict__ XT,
                                                      const float* __restrict__ off,
                                                      const ushort_t* __restrict__ wmf,
                                                      ushort_t* __restrict__ FT) {
    __shared__ ushort_t b_lds[64][264];
    int u = blockIdx.x & 7, v = blockIdx.x >> 3;
    int lin = u * 96 + v;
    int z = lin >> 6, h = lin & 63;
    int b = z & 3, pair = z >> 2;

    const ushort_t* xtz = XT + (size_t)z * HW * 320;
    const float* offp = off + (size_t)z * 72 * HW;
    int tid = threadIdx.x;
    int lane = tid & 63;
    int g = tid >> 6;
    int l15 = tid & 15;
    int kq = (tid >> 4) & 3;

    f32x4 acc[4][4];
#pragma unroll
    for (int m = 0; m < 4; ++m)
#pragma unroll
        for (int n = 0; n < 4; ++n) acc[m][n] = (f32x4){0.f, 0.f, 0.f, 0.f};

    for (int k = 0; k < 9; ++k) {
        __syncthreads();
        {
            float oy = offp[(size_t)(g * 18 + k * 2 + 0) * HW + h * WW + lane];
            float ox = offp[(size_t)(g * 18 + k * 2 + 1) * HW + h * WW + lane];
            float py = (float)h + (float)(k / 3 - 1) + oy;
            float px = (float)lane + (float)(k % 3 - 1) + ox;
            float y0f = floorf(py), x0f = floorf(px);
            float fy = py - y0f, fx = px - x0f;
            int y0 = (int)y0f, x0 = (int)x0f;
            int y1 = y0 + 1, x1 = x0 + 1;
            bool vy0 = (y0 >= 0) && (y0 < HH);
            bool vy1 = (y1 >= 0) && (y1 < HH);
            bool vx0 = (x0 >= 0) && (x0 < WW);
            bool vx1 = (x1 >= 0) && (x1 < WW);
            float w00 = (1.f - fy) * (1.f - fx) * ((vy0 && vx0) ? 1.f : 0.f);
            float w01 = (1.f - fy) * fx * ((vy0 && vx1) ? 1.f : 0.f);
            float w10 = fy * (1.f - fx) * ((vy1 && vx0) ? 1.f : 0.f);
            float w11 = fy * fx * ((vy1 && vx1) ? 1.f : 0.f);
            int cy0 = min(max(y0, 0), HH - 1), cy1 = min(max(y1, 0), HH - 1);
            int cx0 = min(max(x0, 0), WW - 1), cx1 = min(max(x1, 0), WW - 1);
            const ushort_t* p00 = xtz + (size_t)(cy0 * WW + cx0) * 320 + g * 64;
            const ushort_t* p01 = xtz + (size_t)(cy0 * WW + cx1) * 320 + g * 64;
            const ushort_t* p10 = xtz + (size_t)(cy1 * WW + cx0) * 320 + g * 64;
            const ushort_t* p11 = xtz + (size_t)(cy1 * WW + cx1) * 320 + g * 64;
#pragma unroll
            for (int c0 = 0; c0 < 64; c0 += 8) {
                uint4 a00 = *reinterpret_cast<const uint4*>(p00 + c0);
                uint4 a01 = *reinterpret_cast<const uint4*>(p01 + c0);
                uint4 a10 = *reinterpret_cast<const uint4*>(p10 + c0);
                uint4 a11 = *reinterpret_cast<const uint4*>(p11 + c0);
                unsigned pw[4];
                const unsigned* u00 = &a00.x;
                const unsigned* u01 = &a01.x;
                const unsigned* u10 = &a10.x;
                const unsigned* u11 = &a11.x;
#pragma unroll
                for (int q = 0; q < 4; ++q) {
                    float s0 = w00 * bflo(u00[q]) + w01 * bflo(u01[q]) +
                               w10 * bflo(u10[q]) + w11 * bflo(u11[q]);
                    float s1 = w00 * bfhi(u00[q]) + w01 * bfhi(u01[q]) +
                               w10 * bfhi(u10[q]) + w11 * bfhi(u11[q]);
                    pw[q] = (unsigned)f2bf(s0) | ((unsigned)f2bf(s1) << 16);
                }
                *reinterpret_cast<uint4*>(&b_lds[lane][g * 64 + c0]) =
                    make_uint4(pw[0], pw[1], pw[2], pw[3]);
            }
        }
        __syncthreads();
        const ushort_t* wkbase = wmf + (size_t)k * 65536 + (size_t)(g * 64) * 256;
#pragma unroll 1
        for (int cs = 0; cs < 8; ++cs) {
            int c0 = cs * 32;
            short8 bfr[4], afr[4];
#pragma unroll
            for (int n = 0; n < 4; ++n)
                bfr[n] = *reinterpret_cast<const short8*>(&b_lds[n * 16 + l15][c0 + kq * 8]);
#pragma unroll
            for (int m = 0; m < 4; ++m)
                afr[m] = *reinterpret_cast<const short8*>(
                    wkbase + (size_t)(m * 16 + l15) * 256 + c0 + kq * 8);
#pragma unroll
            for (int m = 0; m < 4; ++m)
#pragma unroll
                for (int n = 0; n < 4; ++n)
                    acc[m][n] = __builtin_amdgcn_mfma_f32_16x16x32_bf16(afr[m], bfr[n],
                                                                        acc[m][n], 0, 0, 0);
        }
    }
    __syncthreads();
#pragma unroll
    for (int m = 0; m < 4; ++m)
#pragma unroll
        for (int n = 0; n < 4; ++n) {
            unsigned lo = (unsigned)f2bf(acc[m][n][0]) | ((unsigned)f2bf(acc[m][n][1]) << 16);
            unsigned hi = (unsigned)f2bf(acc[m][n][2]) | ((unsigned)f2bf(acc[m][n][3]) << 16);
            uint2 vv = make_uint2(lo, hi);
            *reinterpret_cast<uint2*>(&b_lds[n * 16 + l15][g * 64 + m * 16 + kq * 4]) = vv;
        }
    __syncthreads();
    int wout = tid >> 2, ch = tid & 3;
    ushort_t* dst = FT + ((size_t)b * HW + h * 64 + wout) * 1024 + pair * 256 + ch * 64;
    const ushort_t* srcl = &b_lds[wout][ch * 64];
#pragma unroll
    for (int i = 0; i < 8; ++i) {
        uint4 vv = *reinterpret_cast<const uint4*>(srcl + i * 8);
        *reinterpret_cast<uint4*>(dst + i * 8) = vv;
    }
}

// ---------------- FT build (y part) ----------------
__global__ void __launch_bounds__(256) ft_build_y(const float* __restrict__ in,
                                                  ushort_t* __restrict__ FT) {
    __shared__ ushort_t tileT[64][72];
    int hw0 = blockIdx.x * 64;
    int ct = blockIdx.y;
    int b = blockIdx.z;
    int t = threadIdx.x;
    int cil = t >> 2, q = t & 3;
    const float* sp = in + ((size_t)(b * 4 + 3) * 256 + ct * 64 + cil) * HW + hw0 + q * 16;
#pragma unroll
    for (int i = 0; i < 16; ++i) tileT[q * 16 + i][cil] = f2bf(sp[i]);
    __syncthreads();
    int hwl = t >> 2;
    const uint4* tp = reinterpret_cast<const uint4*>(&tileT[hwl][q * 16]);
    uint4* op = reinterpret_cast<uint4*>(
        &FT[((size_t)b * HW + hw0 + hwl) * 1024 + 768 + ct * 64 + q * 16]);
    op[0] = tp[0];
    op[1] = tp[1];
}

// ---------------- fusion conv via MFMA bf16 ----------------
__global__ void __launch_bounds__(256, 2) fusion_mfma(const ushort_t* __restrict__ FT,
                                                      const ushort_t* __restrict__ wmf,
                                                      float* __restrict__ out) {
    __shared__ ushort_t a_lds[64][40];
    __shared__ ushort_t b_lds[128][40];
    int o0 = blockIdx.x * 64;
    int n0 = blockIdx.y * 128;
    int b = blockIdx.z;
    int t = threadIdx.x;
    int wid = t >> 6;
    int lane = t & 63;
    int l15 = lane & 15;
    int kq = lane >> 4;
    int r2 = t >> 1, half = t & 1;
    int hwB = n0 + r2;
    int hB = hwB >> 6, wB = hwB & 63;
    const ushort_t* ftb = FT + (size_t)b * HW * 1024;

    f32x4 acc[4][2];
#pragma unroll
    for (int fm = 0; fm < 4; ++fm)
#pragma unroll
        for (int fn = 0; fn < 2; ++fn) acc[fm][fn] = (f32x4){0.f, 0.f, 0.f, 0.f};

    for (int kk = 0; kk < 288; ++kk) {
        int tap = kk >> 5;
        int ci0 = (kk & 31) << 5;
        int kh = tap / 3;
        int kw = tap - kh * 3;
        int hP = hB + kh - 1;
        int wP = wB + kw - 1;
        bool valid = (hP >= 0) && (hP < HH) && (wP >= 0) && (wP < WW);
        uint4 vb0 = make_uint4(0, 0, 0, 0), vb1 = make_uint4(0, 0, 0, 0);
        if (valid) {
            const uint4* gp = reinterpret_cast<const uint4*>(
                ftb + (size_t)(hP * WW + wP) * 1024 + ci0 + half * 16);
            vb0 = gp[0];
            vb1 = gp[1];
        }
        uint4 va0, va1;
        if (t < 128) {
            const uint4* ga = reinterpret_cast<const uint4*>(
                wmf + ((size_t)(tap * 256 + o0 + r2) << 10) + ci0 + half * 16);
            va0 = ga[0];
            va1 = ga[1];
        }
        __syncthreads();
        {
            uint4* bp = reinterpret_cast<uint4*>(&b_lds[r2][half * 16]);
            bp[0] = vb0;
            bp[1] = vb1;
            if (t < 128) {
                uint4* ap = reinterpret_cast<uint4*>(&a_lds[r2][half * 16]);
                ap[0] = va0;
                ap[1] = va1;
            }
        }
        __syncthreads();
        short8 af[4], bf[2];
#pragma unroll
        for (int fm = 0; fm < 4; ++fm)
            af[fm] = *reinterpret_cast<const short8*>(&a_lds[fm * 16 + l15][kq * 8]);
#pragma unroll
        for (int fn = 0; fn < 2; ++fn)
            bf[fn] = *reinterpret_cast<const short8*>(&b_lds[wid * 32 + fn * 16 + l15][kq * 8]);
#pragma unroll
        for (int fm = 0; fm < 4; ++fm)
#pragma unroll
            for (int fn = 0; fn < 2; ++fn)
                acc[fm][fn] = __builtin_amdgcn_mfma_f32_16x16x32_bf16(af[fm], bf[fn],
                                                                      acc[fm][fn], 0, 0, 0);
    }
    float* ob = out + ((size_t)b * 256 + o0) * HW + n0 + wid * 32;
#pragma unroll
    for (int fm = 0; fm < 4; ++fm)
#pragma unroll
        for (int fn = 0; fn < 2; ++fn)
#pragma unroll
            for (int e = 0; e < 4; ++e) {
                int o_l = fm * 16 + 4 * kq + e;
                ob[(size_t)o_l * HW + fn * 16 + l15] = acc[fm][fn][e];
            }
}

extern "C" void kernel_launch(void* const* d_in, const int* in_sizes, int n_in,
                              void* d_out, int out_size, void* d_ws, size_t ws_size,
                              hipStream_t stream) {
    const float* in   = (const float*)d_in[0];   // [16,256,64,64]
    const float* wOff = (const float*)d_in[1];   // [72,305,3,3]
    const float* wDef = (const float*)d_in[2];   // [256,256,3,3]
    const float* wFus = (const float*)d_in[3];   // [256,1024,3,3]
    float* out = (float*)d_out;                  // [4,256,64,64]
    char* base = (char*)d_ws;

    // XT alive through deform. corrP (38.5 MB) overlays FT+offB start — dead
    // after corr_reduce, before offconv writes offB / ft_build_y writes FT.
    ushort_t* XT     = (ushort_t*)base;                 // 31,457,280 B
    ushort_t* FT     = (ushort_t*)(base + 31457280);    // 33,554,432 B -> 65,011,712
    float* corrP     = (float*)(base + 31457280);       // 38,535,168 B -> 69,992,448 (dead early)
    float* offB      = (float*)(base + 65011712);       // 14,155,776 B -> 79,167,488
    ushort_t* wdefMF = (ushort_t*)(base + 79167488);    //  1,179,648 B -> 80,347,136
    ushort_t* woffMF = (ushort_t*)(base + 80347136);    //    460,800 B -> 80,807,936
    ushort_t* wfusMF = (ushort_t*)(base + 80807936);    //  4,718,592 B -> 85,526,528

    hipLaunchKernelGGL(prep_wdef, dim3((9 * 256 * 256 + 255) / 256), dim3(256), 0, stream,
                       wDef, wdefMF);
    hipLaunchKernelGGL(prep_woff, dim3((9 * 80 * 320 + 255) / 256), dim3(256), 0, stream,
                       wOff, woffMF);
    hipLaunchKernelGGL(prep_wfus, dim3((9 * 256 * 1024 + 255) / 256), dim3(256), 0, stream,
                       wFus, wfusMF);
    hipLaunchKernelGGL(xt_build, dim3(64, 4, 12), dim3(256), 0, stream, in, XT);
    hipLaunchKernelGGL(corr_partial, dim3(64, 12, 4), dim3(256), 0, stream, in, corrP);
    hipLaunchKernelGGL(corr_reduce, dim3(64, 12), dim3(256), 0, stream, corrP, XT);
    hipLaunchKernelGGL(offconv_mfma, dim3(32, 12), dim3(256), 0, stream, XT, woffMF, offB);
    hipLaunchKernelGGL(ft_build_y, dim3(64, 4, 4), dim3(256), 0, stream, in, FT);
    hipLaunchKernelGGL(deform_mfma, dim3(768), dim3(256), 0, stream, XT, offB, wdefMF, FT);
    hipLaunchKernelGGL(fusion_mfma, dim3(4, 32, 4), dim3(256), 0, stream, FT, wfusMF, out);
}

// Round 10
// 588.790 us; speedup vs baseline: 11.5973x; 1.0917x over previous
//
#include <hip/hip_runtime.h>

#define HH 64
#define WW 64
#define HW 4096
#define CC 256
#define BB 4
#define GG 4
#define NPAIR 3

typedef __attribute__((ext_vector_type(8))) short short8;
typedef __attribute__((ext_vector_type(4))) float f32x4;
typedef unsigned short ushort_t;

__device__ inline ushort_t f2bf(float x) {
    unsigned int u = __float_as_uint(x);
    unsigned int r = (u + 0x7fffu + ((u >> 16) & 1u)) >> 16;
    return (ushort_t)r;
}
__device__ inline float bflo(unsigned u) { return __uint_as_float(u << 16); }
__device__ inline float bfhi(unsigned u) { return __uint_as_float(u & 0xffff0000u); }

// ---------------- weight preps ----------------
__global__ void prep_wdef(const float* __restrict__ wd, ushort_t* __restrict__ wmf) {
    int idx = blockIdx.x * 256 + threadIdx.x;  // 9*256*256
    if (idx >= 9 * 256 * 256) return;
    int k = idx >> 16;
    int rem = idx & 65535;
    int o = rem >> 8;
    int c = rem & 255;
    wmf[idx] = f2bf(wd[((size_t)(o * 256 + c)) * 9 + k]);
}

__global__ void prep_woff(const float* __restrict__ wo, ushort_t* __restrict__ wmf) {
    int idx = blockIdx.x * 256 + threadIdx.x;  // 9*80*320
    if (idx >= 9 * 80 * 320) return;
    int k = idx / (80 * 320);
    int rem = idx % (80 * 320);
    int o = rem / 320;
    int ci = rem % 320;
    wmf[idx] = (o < 72 && ci < 305) ? f2bf(wo[((size_t)o * 305 + ci) * 9 + k]) : (ushort_t)0;
}

__global__ void prep_wfus(const float* __restrict__ wf, ushort_t* __restrict__ wmf) {
    int idx = blockIdx.x * 256 + threadIdx.x;  // 9*256*1024
    if (idx >= 9 * 256 * 1024) return;
    int k = idx / (256 * 1024);
    int rem = idx % (256 * 1024);
    int o = rem / 1024;
    int ci = rem % 1024;
    wmf[idx] = f2bf(wf[((size_t)o * 1024 + ci) * 9 + k]);
}

// ---------------- XT build: in fp32 [c][hw] -> XT bf16 [z][hw][320] cols 0..255 ----------------
__global__ void __launch_bounds__(256) xt_build(const float* __restrict__ in,
                                                ushort_t* __restrict__ XT) {
    __shared__ ushort_t tileT[64][72];
    int hw0 = blockIdx.x * 64;
    int ct = blockIdx.y;
    int z = blockIdx.z;
    int pair = z >> 2, b = z & 3;
    int t = threadIdx.x;
    int cil = t >> 2, q = t & 3;
    const float* sp = in + ((size_t)(b * 4 + pair) * 256 + ct * 64 + cil) * HW + hw0 + q * 16;
#pragma unroll
    for (int i = 0; i < 16; ++i) tileT[q * 16 + i][cil] = f2bf(sp[i]);
    __syncthreads();
    int hwl = t >> 2;
    const uint4* tp = reinterpret_cast<const uint4*>(&tileT[hwl][q * 16]);
    uint4* op = reinterpret_cast<uint4*>(
        &XT[((size_t)z * HW + hw0 + hwl) * 320 + ct * 64 + q * 16]);
    op[0] = tp[0];
    op[1] = tp[1];
}

// ---------------- correlation partials (channel-split x4) ----------------
__global__ void __launch_bounds__(256, 8) corr_partial(const float* __restrict__ in,
                                                       float* __restrict__ P) {
    __shared__ float x1l[8][64];
    __shared__ float x2l[8][7][76];
    int h = blockIdx.x, z = blockIdx.y, cg = blockIdx.z;
    int pair = z >> 2, b = z & 3;
    const float* x1 = in + (size_t)(b * GG + pair) * CC * HW + h * WW;
    const float* x2 = in + (size_t)(b * GG + 3) * CC * HW;
    int tid = threadIdx.x;
    int w = tid & 63;
    int dg = tid >> 6;

    float acc[2][7];
#pragma unroll
    for (int i = 0; i < 2; ++i)
#pragma unroll
        for (int j = 0; j < 7; ++j) acc[i][j] = 0.f;

    for (int c0 = cg * 64; c0 < cg * 64 + 64; c0 += 8) {
        __syncthreads();
#pragma unroll
        for (int idx = tid; idx < 512; idx += 256) {
            int cc = idx >> 6, ww = idx & 63;
            x1l[cc][ww] = x1[(size_t)(c0 + cc) * HW + ww];
        }
        for (int idx = tid; idx < 8 * 7 * 76; idx += 256) {
            int cc = idx / 532;
            int rem = idx - cc * 532;
            int r = rem / 76;
            int cl = rem - r * 76;
            int row = h + 2 * (r - 3);
            int col = cl - 6;
            float v = 0.f;
            if (row >= 0 && row < HH && col >= 0 && col < WW)
                v = x2[(size_t)(c0 + cc) * HW + row * WW + col];
            x2l[cc][r][cl] = v;
        }
        __syncthreads();
#pragma unroll
        for (int cc = 0; cc < 8; ++cc) {
            float x1v = x1l[cc][w];
#pragma unroll
            for (int i = 0; i < 2; ++i) {
                int di = dg * 2 + i;
                if (di < 7) {
#pragma unroll
                    for (int dj = 0; dj < 7; ++dj)
                        acc[i][dj] += x1v * x2l[cc][di][w + 2 * dj];
                }
            }
        }
    }
    float* pp = P + ((size_t)(cg * 12 + z) * 49) * HW + h * WW + w;
#pragma unroll
    for (int i = 0; i < 2; ++i) {
        int di = dg * 2 + i;
        if (di < 7) {
#pragma unroll
            for (int dj = 0; dj < 7; ++dj)
                pp[(size_t)(di * 7 + dj) * HW] = acc[i][dj];
        }
    }
}

// ---------------- corr reduce ----------------
__global__ void __launch_bounds__(256) corr_reduce(const float* __restrict__ P,
                                                   ushort_t* __restrict__ XT) {
    int h = blockIdx.x, z = blockIdx.y;
    int tid = threadIdx.x;
    int w = tid & 63;
    int dg = tid >> 6;
    const size_t cgs = (size_t)12 * 49 * HW;
    ushort_t* xrow = XT + ((size_t)z * HW + h * WW + w) * 320;
#pragma unroll
    for (int i = 0; i < 2; ++i) {
        int di = dg * 2 + i;
        if (di < 7) {
#pragma unroll
            for (int dj = 0; dj < 7; ++dj) {
                int d = di * 7 + dj;
                const float* pp = P + ((size_t)z * 49 + d) * HW + h * WW + w;
                float s = pp[0] + pp[cgs] + pp[2 * cgs] + pp[3 * cgs];
                xrow[256 + d] = f2bf(s * (1.f / 256.f));
            }
        }
    }
    if (dg == 3) {
#pragma unroll
        for (int p = 0; p < 15; ++p) xrow[305 + p] = 0;
    }
}

// ---------------- offset conv via MFMA bf16 ----------------
__global__ void __launch_bounds__(256, 2) offconv_mfma(const ushort_t* __restrict__ XT,
                                                       const ushort_t* __restrict__ wmf,
                                                       float* __restrict__ off) {
    __shared__ ushort_t a_lds[80][40];
    __shared__ ushort_t b_lds[128][40];
    int n0 = blockIdx.x * 128;
    int z = blockIdx.y;
    int t = threadIdx.x;
    int wid = t >> 6;
    int lane = t & 63;
    int l15 = lane & 15;
    int kq = lane >> 4;
    int r2 = t >> 1, half = t & 1;
    int hwB = n0 + r2;
    int hB = hwB >> 6, wB = hwB & 63;
    const ushort_t* xtb = XT + (size_t)z * HW * 320;

    f32x4 acc[5][2];
#pragma unroll
    for (int m = 0; m < 5; ++m)
#pragma unroll
        for (int n = 0; n < 2; ++n) acc[m][n] = (f32x4){0.f, 0.f, 0.f, 0.f};

    for (int tap = 0; tap < 9; ++tap) {
        int kh = tap / 3;
        int kw = tap - kh * 3;
        int hP = hB + kh - 1;
        int wP = wB + kw - 1;
        bool valid = (hP >= 0) && (hP < HH) && (wP >= 0) && (wP < WW);
        const ushort_t* brow = xtb + (size_t)(hP * WW + wP) * 320;
#pragma unroll 1
        for (int cs = 0; cs < 10; ++cs) {
            int ci0 = cs * 32;
            uint4 vb0 = make_uint4(0, 0, 0, 0), vb1 = make_uint4(0, 0, 0, 0);
            if (valid) {
                const uint4* gp = reinterpret_cast<const uint4*>(brow + ci0 + half * 16);
                vb0 = gp[0];
                vb1 = gp[1];
            }
            uint4 va0, va1;
            if (t < 160) {
                const uint4* ga = reinterpret_cast<const uint4*>(
                    wmf + ((size_t)tap * 80 + r2) * 320 + ci0 + half * 16);
                va0 = ga[0];
                va1 = ga[1];
            }
            __syncthreads();
            {
                uint4* bp = reinterpret_cast<uint4*>(&b_lds[r2][half * 16]);
                bp[0] = vb0;
                bp[1] = vb1;
                if (t < 160) {
                    uint4* ap = reinterpret_cast<uint4*>(&a_lds[r2][half * 16]);
                    ap[0] = va0;
                    ap[1] = va1;
                }
            }
            __syncthreads();
            short8 af[5], bf[2];
#pragma unroll
            for (int m = 0; m < 5; ++m)
                af[m] = *reinterpret_cast<const short8*>(&a_lds[m * 16 + l15][kq * 8]);
#pragma unroll
            for (int n = 0; n < 2; ++n)
                bf[n] = *reinterpret_cast<const short8*>(&b_lds[wid * 32 + n * 16 + l15][kq * 8]);
#pragma unroll
            for (int m = 0; m < 5; ++m)
#pragma unroll
                for (int n = 0; n < 2; ++n)
                    acc[m][n] = __builtin_amdgcn_mfma_f32_16x16x32_bf16(af[m], bf[n],
                                                                        acc[m][n], 0, 0, 0);
        }
    }
    float* ob = off + (size_t)z * 72 * HW + n0 + wid * 32;
#pragma unroll
    for (int m = 0; m < 5; ++m)
#pragma unroll
        for (int n = 0; n < 2; ++n)
#pragma unroll
            for (int e = 0; e < 4; ++e) {
                int o_l = m * 16 + kq * 4 + e;
                if (o_l < 72) ob[(size_t)o_l * HW + n * 16 + l15] = acc[m][n][e];
            }
}

// ---------------- deformable conv via MFMA bf16 (samples from XT) ----------------
__global__ void __launch_bounds__(256, 3) deform_mfma(const ushort_t* __restrict__ XT,
                                                      const float* __restrict__ off,
                                                      const ushort_t* __restrict__ wmf,
                                                      ushort_t* __restrict__ FT) {
    __shared__ ushort_t b_lds[64][264];
    int u = blockIdx.x & 7, v = blockIdx.x >> 3;
    int lin = u * 96 + v;
    int z = lin >> 6, h = lin & 63;
    int b = z & 3, pair = z >> 2;

    const ushort_t* xtz = XT + (size_t)z * HW * 320;
    const float* offp = off + (size_t)z * 72 * HW;
    int tid = threadIdx.x;
    int lane = tid & 63;
    int g = tid >> 6;
    int l15 = tid & 15;
    int kq = (tid >> 4) & 3;

    f32x4 acc[4][4];
#pragma unroll
    for (int m = 0; m < 4; ++m)
#pragma unroll
        for (int n = 0; n < 4; ++n) acc[m][n] = (f32x4){0.f, 0.f, 0.f, 0.f};

    for (int k = 0; k < 9; ++k) {
        __syncthreads();
        {
            float oy = offp[(size_t)(g * 18 + k * 2 + 0) * HW + h * WW + lane];
            float ox = offp[(size_t)(g * 18 + k * 2 + 1) * HW + h * WW + lane];
            float py = (float)h + (float)(k / 3 - 1) + oy;
            float px = (float)lane + (float)(k % 3 - 1) + ox;
            float y0f = floorf(py), x0f = floorf(px);
            float fy = py - y0f, fx = px - x0f;
            int y0 = (int)y0f, x0 = (int)x0f;
            int y1 = y0 + 1, x1 = x0 + 1;
            bool vy0 = (y0 >= 0) && (y0 < HH);
            bool vy1 = (y1 >= 0) && (y1 < HH);
            bool vx0 = (x0 >= 0) && (x0 < WW);
            bool vx1 = (x1 >= 0) && (x1 < WW);
            float w00 = (1.f - fy) * (1.f - fx) * ((vy0 && vx0) ? 1.f : 0.f);
            float w01 = (1.f - fy) * fx * ((vy0 && vx1) ? 1.f : 0.f);
            float w10 = fy * (1.f - fx) * ((vy1 && vx0) ? 1.f : 0.f);
            float w11 = fy * fx * ((vy1 && vx1) ? 1.f : 0.f);
            int cy0 = min(max(y0, 0), HH - 1), cy1 = min(max(y1, 0), HH - 1);
            int cx0 = min(max(x0, 0), WW - 1), cx1 = min(max(x1, 0), WW - 1);
            const ushort_t* p00 = xtz + (size_t)(cy0 * WW + cx0) * 320 + g * 64;
            const ushort_t* p01 = xtz + (size_t)(cy0 * WW + cx1) * 320 + g * 64;
            const ushort_t* p10 = xtz + (size_t)(cy1 * WW + cx0) * 320 + g * 64;
            const ushort_t* p11 = xtz + (size_t)(cy1 * WW + cx1) * 320 + g * 64;
#pragma unroll
            for (int c0 = 0; c0 < 64; c0 += 8) {
                uint4 a00 = *reinterpret_cast<const uint4*>(p00 + c0);
                uint4 a01 = *reinterpret_cast<const uint4*>(p01 + c0);
                uint4 a10 = *reinterpret_cast<const uint4*>(p10 + c0);
                uint4 a11 = *reinterpret_cast<const uint4*>(p11 + c0);
                unsigned pw[4];
                const unsigned* u00 = &a00.x;
                const unsigned* u01 = &a01.x;
                const unsigned* u10 = &a10.x;
                const unsigned* u11 = &a11.x;
#pragma unroll
                for (int q = 0; q < 4; ++q) {
                    float s0 = w00 * bflo(u00[q]) + w01 * bflo(u01[q]) +
                               w10 * bflo(u10[q]) + w11 * bflo(u11[q]);
                    float s1 = w00 * bfhi(u00[q]) + w01 * bfhi(u01[q]) +
                               w10 * bfhi(u10[q]) + w11 * bfhi(u11[q]);
                    pw[q] = (unsigned)f2bf(s0) | ((unsigned)f2bf(s1) << 16);
                }
                *reinterpret_cast<uint4*>(&b_lds[lane][g * 64 + c0]) =
                    make_uint4(pw[0], pw[1], pw[2], pw[3]);
            }
        }
        __syncthreads();
        const ushort_t* wkbase = wmf + (size_t)k * 65536 + (size_t)(g * 64) * 256;
#pragma unroll 1
        for (int cs = 0; cs < 8; ++cs) {
            int c0 = cs * 32;
            short8 bfr[4], afr[4];
#pragma unroll
            for (int n = 0; n < 4; ++n)
                bfr[n] = *reinterpret_cast<const short8*>(&b_lds[n * 16 + l15][c0 + kq * 8]);
#pragma unroll
            for (int m = 0; m < 4; ++m)
                afr[m] = *reinterpret_cast<const short8*>(
                    wkbase + (size_t)(m * 16 + l15) * 256 + c0 + kq * 8);
#pragma unroll
            for (int m = 0; m < 4; ++m)
#pragma unroll
                for (int n = 0; n < 4; ++n)
                    acc[m][n] = __builtin_amdgcn_mfma_f32_16x16x32_bf16(afr[m], bfr[n],
                                                                        acc[m][n], 0, 0, 0);
        }
    }
    __syncthreads();
#pragma unroll
    for (int m = 0; m < 4; ++m)
#pragma unroll
        for (int n = 0; n < 4; ++n) {
            unsigned lo = (unsigned)f2bf(acc[m][n][0]) | ((unsigned)f2bf(acc[m][n][1]) << 16);
            unsigned hi = (unsigned)f2bf(acc[m][n][2]) | ((unsigned)f2bf(acc[m][n][3]) << 16);
            uint2 vv = make_uint2(lo, hi);
            *reinterpret_cast<uint2*>(&b_lds[n * 16 + l15][g * 64 + m * 16 + kq * 4]) = vv;
        }
    __syncthreads();
    int wout = tid >> 2, ch = tid & 3;
    ushort_t* dst = FT + ((size_t)b * HW + h * 64 + wout) * 1024 + pair * 256 + ch * 64;
    const ushort_t* srcl = &b_lds[wout][ch * 64];
#pragma unroll
    for (int i = 0; i < 8; ++i) {
        uint4 vv = *reinterpret_cast<const uint4*>(srcl + i * 8);
        *reinterpret_cast<uint4*>(dst + i * 8) = vv;
    }
}

// ---------------- FT build (y part) ----------------
__global__ void __launch_bounds__(256) ft_build_y(const float* __restrict__ in,
                                                  ushort_t* __restrict__ FT) {
    __shared__ ushort_t tileT[64][72];
    int hw0 = blockIdx.x * 64;
    int ct = blockIdx.y;
    int b = blockIdx.z;
    int t = threadIdx.x;
    int cil = t >> 2, q = t & 3;
    const float* sp = in + ((size_t)(b * 4 + 3) * 256 + ct * 64 + cil) * HW + hw0 + q * 16;
#pragma unroll
    for (int i = 0; i < 16; ++i) tileT[q * 16 + i][cil] = f2bf(sp[i]);
    __syncthreads();
    int hwl = t >> 2;
    const uint4* tp = reinterpret_cast<const uint4*>(&tileT[hwl][q * 16]);
    uint4* op = reinterpret_cast<uint4*>(
        &FT[((size_t)b * HW + hw0 + hwl) * 1024 + 768 + ct * 64 + q * 16]);
    op[0] = tp[0];
    op[1] = tp[1];
}

// ---------------- fusion conv via MFMA bf16 (halo-staged B, XCD-chunked) ----------------
// 1-D grid 512: lin = (bid&7)*64 + bid>>3; lin -> (ot, n-tile, b) with the 4
// o-tiles of one (n,b) adjacent -> same XCD -> B rows fetched once per group.
// Per ci-chunk: stage B halo (4x66 pos x 32 ci) + A (9 taps x 64 o x 32 ci);
// inner 9-tap loop reads B frags at shifted LDS positions.
__global__ void __launch_bounds__(256, 2) fusion_mfma(const ushort_t* __restrict__ FT,
                                                      const ushort_t* __restrict__ wmf,
                                                      float* __restrict__ out) {
    __shared__ ushort_t a_lds[9][64][32];   // 36,864 B
    __shared__ ushort_t b_hal[264][32];     // 16,896 B; pos = r*66 + c
    int lin = ((blockIdx.x & 7) << 6) | (blockIdx.x >> 3);
    int ot = lin & 3;
    int g2 = lin >> 2;
    int n0t = g2 & 31;
    int b = g2 >> 5;
    int o0 = ot * 64;
    int h0 = n0t * 2;  // first of 2 h-rows (128 hw)
    int t = threadIdx.x;
    int wid = t >> 6;
    int lane = t & 63;
    int l15 = lane & 15;
    int kq = lane >> 4;
    const ushort_t* ftb = FT + (size_t)b * HW * 1024;

    f32x4 acc[4][2];
#pragma unroll
    for (int fm = 0; fm < 4; ++fm)
#pragma unroll
        for (int fn = 0; fn < 2; ++fn) acc[fm][fn] = (f32x4){0.f, 0.f, 0.f, 0.f};

#pragma unroll 1
    for (int cs = 0; cs < 32; ++cs) {
        int ci0 = cs * 32;
        __syncthreads();
        // ---- stage B halo: 264 positions x 32 ci (64 B each) ----
        for (int idx = t; idx < 264; idx += 256) {
            int r = idx / 66, c = idx - r * 66;
            int hP = h0 + r - 1, wP = c - 1;
            uint4* dst = reinterpret_cast<uint4*>(&b_hal[idx][0]);
            if (hP >= 0 && hP < HH && wP >= 0 && wP < WW) {
                const uint4* src = reinterpret_cast<const uint4*>(
                    ftb + (size_t)(hP * WW + wP) * 1024 + ci0);
                dst[0] = src[0];
                dst[1] = src[1];
                dst[2] = src[2];
                dst[3] = src[3];
            } else {
                uint4 zz = make_uint4(0, 0, 0, 0);
                dst[0] = zz;
                dst[1] = zz;
                dst[2] = zz;
                dst[3] = zz;
            }
        }
        // ---- stage A: 9 taps x 64 o x 32 ci = 2304 uint4 ----
        for (int idx = t; idx < 2304; idx += 256) {
            int tp = idx >> 8;
            int rem = idx & 255;
            int o = rem >> 2, q = rem & 3;
            *reinterpret_cast<uint4*>(&a_lds[tp][o][q * 8]) =
                *reinterpret_cast<const uint4*>(
                    wmf + ((size_t)(tp * 256 + o0 + o) << 10) + ci0 + q * 8);
        }
        __syncthreads();
        // ---- 9 taps of MFMA from LDS ----
#pragma unroll 1
        for (int tap = 0; tap < 9; ++tap) {
            int kh = tap / 3, kw = tap - kh * 3;
            short8 af[4], bf[2];
#pragma unroll
            for (int m = 0; m < 4; ++m)
                af[m] = *reinterpret_cast<const short8*>(&a_lds[tap][m * 16 + l15][kq * 8]);
#pragma unroll
            for (int n = 0; n < 2; ++n) {
                int p = wid * 32 + n * 16 + l15;  // local hw 0..127
                int pos = ((p >> 6) + kh) * 66 + (p & 63) + kw;
                bf[n] = *reinterpret_cast<const short8*>(&b_hal[pos][kq * 8]);
            }
#pragma unroll
            for (int m = 0; m < 4; ++m)
#pragma unroll
                for (int n = 0; n < 2; ++n)
                    acc[m][n] = __builtin_amdgcn_mfma_f32_16x16x32_bf16(af[m], bf[n],
                                                                        acc[m][n], 0, 0, 0);
        }
    }
    float* ob = out + ((size_t)b * 256 + o0) * HW + h0 * 64 + wid * 32;
#pragma unroll
    for (int fm = 0; fm < 4; ++fm)
#pragma unroll
        for (int fn = 0; fn < 2; ++fn)
#pragma unroll
            for (int e = 0; e < 4; ++e) {
                int o_l = fm * 16 + 4 * kq + e;
                ob[(size_t)o_l * HW + fn * 16 + l15] = acc[fm][fn][e];
            }
}

extern "C" void kernel_launch(void* const* d_in, const int* in_sizes, int n_in,
                              void* d_out, int out_size, void* d_ws, size_t ws_size,
                              hipStream_t stream) {
    const float* in   = (const float*)d_in[0];   // [16,256,64,64]
    const float* wOff = (const float*)d_in[1];   // [72,305,3,3]
    const float* wDef = (const float*)d_in[2];   // [256,256,3,3]
    const float* wFus = (const float*)d_in[3];   // [256,1024,3,3]
    float* out = (float*)d_out;                  // [4,256,64,64]
    char* base = (char*)d_ws;

    ushort_t* XT     = (ushort_t*)base;                 // 31,457,280 B
    ushort_t* FT     = (ushort_t*)(base + 31457280);    // 33,554,432 B -> 65,011,712
    float* corrP     = (float*)(base + 31457280);       // 38,535,168 B (dead early)
    float* offB      = (float*)(base + 65011712);       // 14,155,776 B -> 79,167,488
    ushort_t* wdefMF = (ushort_t*)(base + 79167488);    //  1,179,648 B -> 80,347,136
    ushort_t* woffMF = (ushort_t*)(base + 80347136);    //    460,800 B -> 80,807,936
    ushort_t* wfusMF = (ushort_t*)(base + 80807936);    //  4,718,592 B -> 85,526,528

    hipLaunchKernelGGL(prep_wdef, dim3((9 * 256 * 256 + 255) / 256), dim3(256), 0, stream,
                       wDef, wdefMF);
    hipLaunchKernelGGL(prep_woff, dim3((9 * 80 * 320 + 255) / 256), dim3(256), 0, stream,
                       wOff, woffMF);
    hipLaunchKernelGGL(prep_wfus, dim3((9 * 256 * 1024 + 255) / 256), dim3(256), 0, stream,
                       wFus, wfusMF);
    hipLaunchKernelGGL(xt_build, dim3(64, 4, 12), dim3(256), 0, stream, in, XT);
    hipLaunchKernelGGL(corr_partial, dim3(64, 12, 4), dim3(256), 0, stream, in, corrP);
    hipLaunchKernelGGL(corr_reduce, dim3(64, 12), dim3(256), 0, stream, corrP, XT);
    hipLaunchKernelGGL(offconv_mfma, dim3(32, 12), dim3(256), 0, stream, XT, woffMF, offB);
    hipLaunchKernelGGL(ft_build_y, dim3(64, 4, 4), dim3(256), 0, stream, in, FT);
    hipLaunchKernelGGL(deform_mfma, dim3(768), dim3(256), 0, stream, XT, offB, wdefMF, FT);
    hipLaunchKernelGGL(fusion_mfma, dim3(512), dim3(256), 0, stream, FT, wfusMF, out);
}